// Round 1
// baseline (618.899 us; speedup 1.0000x reference)
//
#include <hip/hip_runtime.h>

// ---------------------------------------------------------------------------
// ImageTextModule: dual cross-attention between text and image feature sets.
//   t = text @ w_text^T + b_text ; i = image @ w_image^T + b_image
//   logits = (t @ i^T) / 32          [4096 x 4096] fp32 (materialized in ws)
//   out0 = softmax_row(logits) * scale_TI @ image
//   out1 = softmax_col(logits)^T * scale_IT @ text
// All GEMMs: bf16 MFMA 16x16x32, fp32 accumulate. Softmax without max-
// subtraction (|logits| < ~3, exp can't overflow) -> stats are plain sums.
// Workspace: 96 MB + 32 KB.
// ---------------------------------------------------------------------------

typedef __bf16 bf16x8 __attribute__((ext_vector_type(8)));
typedef float f32x4 __attribute__((ext_vector_type(4)));

#define N_T 4096
#define N_I 4096
#define DIM 1024
#define LDSS 40  // LDS row stride in bf16 elems: 32 + 8 pad (80 B, keeps 16B align)

__device__ __forceinline__ unsigned short f2bf(float f) {
    unsigned int u = __float_as_uint(f);
    u += 0x7fffu + ((u >> 16) & 1u);  // RNE
    return (unsigned short)(u >> 16);
}

// Stage a 128x32 fp32 tile -> bf16 LDS (optionally exp() first).
// 256 threads: thread t -> row t>>1, 16-elem half (t&1).
template <bool DO_EXP>
__device__ __forceinline__ void stage_f32(const float* __restrict__ src, int ld,
                                          int row0, int k0, unsigned short* dst,
                                          int tid) {
    int r = tid >> 1, c = (tid & 1) << 4;
    const float* p = src + (size_t)(row0 + r) * ld + k0 + c;
    unsigned short* q = dst + r * LDSS + c;
#pragma unroll
    for (int v = 0; v < 4; ++v) {
        float4 f = *(const float4*)(p + v * 4);
        if (DO_EXP) {
            f.x = __expf(f.x); f.y = __expf(f.y);
            f.z = __expf(f.z); f.w = __expf(f.w);
        }
        unsigned int p0 = (unsigned int)f2bf(f.x) | ((unsigned int)f2bf(f.y) << 16);
        unsigned int p1 = (unsigned int)f2bf(f.z) | ((unsigned int)f2bf(f.w) << 16);
        *(unsigned int*)(q + v * 4) = p0;
        *(unsigned int*)(q + v * 4 + 2) = p1;
    }
}

// Stage a 128x32 bf16 tile -> LDS (straight copy, 2x uint4 per thread).
__device__ __forceinline__ void stage_bf16(const unsigned short* __restrict__ src,
                                           int ld, int row0, int k0,
                                           unsigned short* dst, int tid) {
    int r = tid >> 1, c = (tid & 1) << 4;
    const uint4* p = (const uint4*)(src + (size_t)(row0 + r) * ld + k0 + c);
    uint4 x0 = p[0], x1 = p[1];
    *(uint4*)(dst + r * LDSS + c) = x0;
    *(uint4*)(dst + r * LDSS + c + 8) = x1;
}

// One BK=32 MFMA step over the 128x128 tile. Wave w: rows (w>>1)*64, cols (w&1)*64.
__device__ __forceinline__ void mfma_step(const unsigned short* As,
                                          const unsigned short* Bs, f32x4 acc[4][4],
                                          int wrow, int wcol, int lane16, int quad) {
    bf16x8 a[4], b[4];
#pragma unroll
    for (int i = 0; i < 4; ++i) {
        a[i] = *(const bf16x8*)&As[(wrow + i * 16 + lane16) * LDSS + quad * 8];
        b[i] = *(const bf16x8*)&Bs[(wcol + i * 16 + lane16) * LDSS + quad * 8];
    }
#pragma unroll
    for (int i = 0; i < 4; ++i)
#pragma unroll
        for (int j = 0; j < 4; ++j)
            acc[i][j] = __builtin_amdgcn_mfma_f32_16x16x32_bf16(a[i], b[j], acc[i][j], 0, 0, 0);
}

#define GEMM_PROLOG()                                            \
    __shared__ unsigned short As[128 * LDSS];                    \
    __shared__ unsigned short Bs[128 * LDSS];                    \
    int tid = threadIdx.x;                                       \
    int m0 = blockIdx.x * 128, n0 = blockIdx.y * 128;            \
    int lane = tid & 63, wave = tid >> 6;                        \
    int lane16 = lane & 15, quad = lane >> 4;                    \
    int wrow = (wave >> 1) * 64, wcol = (wave & 1) * 64;         \
    f32x4 acc[4][4];                                             \
    {                                                            \
        f32x4 z = {0.f, 0.f, 0.f, 0.f};                          \
        for (int i = 0; i < 4; ++i)                              \
            for (int j = 0; j < 4; ++j) acc[i][j] = z;           \
    }

// ---- projection: C_bf16[M=4096][N=1024] = A_f32 @ W_f32^T + bias ----------
__global__ void __launch_bounds__(256, 2)
gemm_proj(const float* __restrict__ A, const float* __restrict__ W,
          const float* __restrict__ bias, unsigned short* __restrict__ C) {
    GEMM_PROLOG();
    for (int k0 = 0; k0 < DIM; k0 += 32) {
        stage_f32<false>(A, DIM, m0, k0, As, tid);
        stage_f32<false>(W, DIM, n0, k0, Bs, tid);
        __syncthreads();
        mfma_step(As, Bs, acc, wrow, wcol, lane16, quad);
        __syncthreads();
    }
#pragma unroll
    for (int j = 0; j < 4; ++j) {
        int col = n0 + wcol + j * 16 + lane16;
        float bv = bias[col];
#pragma unroll
        for (int i = 0; i < 4; ++i) {
            int rowb = m0 + wrow + i * 16 + quad * 4;
#pragma unroll
            for (int r = 0; r < 4; ++r)
                C[(size_t)(rowb + r) * DIM + col] = f2bf(acc[i][j][r] + bv);
        }
    }
}

// ---- logits: f32[N_T][N_I] = (t_bf16 @ i_bf16^T) / 32 ---------------------
__global__ void __launch_bounds__(256, 2)
gemm_logits(const unsigned short* __restrict__ Tb,
            const unsigned short* __restrict__ Ib, float* __restrict__ logits) {
    GEMM_PROLOG();
    for (int k0 = 0; k0 < DIM; k0 += 32) {
        stage_bf16(Tb, DIM, m0, k0, As, tid);
        stage_bf16(Ib, DIM, n0, k0, Bs, tid);
        __syncthreads();
        mfma_step(As, Bs, acc, wrow, wcol, lane16, quad);
        __syncthreads();
    }
#pragma unroll
    for (int j = 0; j < 4; ++j) {
        int col = n0 + wcol + j * 16 + lane16;
#pragma unroll
        for (int i = 0; i < 4; ++i) {
            int rowb = m0 + wrow + i * 16 + quad * 4;
#pragma unroll
            for (int r = 0; r < 4; ++r)
                logits[(size_t)(rowb + r) * N_I + col] = acc[i][j][r] * 0.03125f;
        }
    }
}

// ---- row sums of exp(logits): lT[t] -----------------------------------------
__global__ void __launch_bounds__(256)
row_sums(const float* __restrict__ logits, float* __restrict__ lT) {
    int row = blockIdx.x;
    const float* p = logits + (size_t)row * N_I;
    float s = 0.f;
    for (int c = threadIdx.x; c < N_I; c += 256) s += __expf(p[c]);
    __shared__ float red[256];
    red[threadIdx.x] = s;
    __syncthreads();
    for (int w = 128; w > 0; w >>= 1) {
        if (threadIdx.x < w) red[threadIdx.x] += red[threadIdx.x + w];
        __syncthreads();
    }
    if (threadIdx.x == 0) lT[row] = red[0];
}

// ---- col sums of exp(logits): lI[i] (partial per 128-row chunk + atomicAdd) --
__global__ void __launch_bounds__(256)
col_sums(const float* __restrict__ logits, float* __restrict__ lI) {
    int col = blockIdx.x * 256 + threadIdx.x;
    int r0 = blockIdx.y * 128;
    float s = 0.f;
    for (int r = 0; r < 128; ++r) s += __expf(logits[(size_t)(r0 + r) * N_I + col]);
    atomicAdd(&lI[col], s);
}

// ---- out0[t][d] = (scale_TI / lT[t]) * sum_c exp(logits[t][c]) * img[c][d] --
__global__ void __launch_bounds__(256, 2)
attn_TI(const float* __restrict__ logits, const unsigned short* __restrict__ imgT,
        const float* __restrict__ lT, const float* __restrict__ scaleTI,
        float* __restrict__ out0) {
    GEMM_PROLOG();
    for (int k0 = 0; k0 < N_I; k0 += 32) {
        stage_f32<true>(logits, N_I, m0, k0, As, tid);  // p = exp(logit), bf16
        stage_bf16(imgT, N_I, n0, k0, Bs, tid);
        __syncthreads();
        mfma_step(As, Bs, acc, wrow, wcol, lane16, quad);
        __syncthreads();
    }
    float sc = scaleTI[0];
#pragma unroll
    for (int i = 0; i < 4; ++i) {
        int rowb = m0 + wrow + i * 16 + quad * 4;
        float fac[4];
#pragma unroll
        for (int r = 0; r < 4; ++r) fac[r] = sc / lT[rowb + r];
#pragma unroll
        for (int j = 0; j < 4; ++j) {
            int col = n0 + wcol + j * 16 + lane16;
#pragma unroll
            for (int r = 0; r < 4; ++r)
                out0[(size_t)(rowb + r) * DIM + col] = acc[i][j][r] * fac[r];
        }
    }
}

// ---- out1[i][d] = (scale_IT / lI[i]) * sum_t exp(logits[t][i]) * text[t][d] --
__global__ void __launch_bounds__(256, 2)
attn_IT(const float* __restrict__ logits, const unsigned short* __restrict__ textT,
        const float* __restrict__ lI, const float* __restrict__ scaleIT,
        float* __restrict__ out1) {
    GEMM_PROLOG();
    for (int k0 = 0; k0 < N_T; k0 += 32) {
        // A tile: As[mm][kk] = exp(logits[k0+kk][m0+mm])  (transposed read)
        {
            int kk = tid >> 3, c0 = (tid & 7) << 4;
            const float* p = logits + (size_t)(k0 + kk) * N_I + m0 + c0;
#pragma unroll
            for (int v = 0; v < 4; ++v) {
                float4 f = *(const float4*)(p + v * 4);
                As[(c0 + v * 4 + 0) * LDSS + kk] = f2bf(__expf(f.x));
                As[(c0 + v * 4 + 1) * LDSS + kk] = f2bf(__expf(f.y));
                As[(c0 + v * 4 + 2) * LDSS + kk] = f2bf(__expf(f.z));
                As[(c0 + v * 4 + 3) * LDSS + kk] = f2bf(__expf(f.w));
            }
        }
        stage_bf16(textT, N_T, n0, k0, Bs, tid);
        __syncthreads();
        mfma_step(As, Bs, acc, wrow, wcol, lane16, quad);
        __syncthreads();
    }
    float sc = scaleIT[0];
#pragma unroll
    for (int i = 0; i < 4; ++i) {
        int rowb = m0 + wrow + i * 16 + quad * 4;
        float fac[4];
#pragma unroll
        for (int r = 0; r < 4; ++r) fac[r] = sc / lI[rowb + r];
#pragma unroll
        for (int j = 0; j < 4; ++j) {
            int col = n0 + wcol + j * 16 + lane16;
#pragma unroll
            for (int r = 0; r < 4; ++r)
                out1[(size_t)(rowb + r) * DIM + col] = acc[i][j][r] * fac[r];
        }
    }
}

// ---- transpose + fp32->bf16: in[R][C] -> out[C][R] --------------------------
__global__ void __launch_bounds__(256)
transpose_cvt(const float* __restrict__ in, unsigned short* __restrict__ out,
              int R, int C) {
    __shared__ float tile[32][33];
    int c0 = blockIdx.x * 32, r0 = blockIdx.y * 32;
    int tx = threadIdx.x & 31, ty = threadIdx.x >> 5;  // 32 x 8
#pragma unroll
    for (int i = ty; i < 32; i += 8)
        tile[i][tx] = in[(size_t)(r0 + i) * C + c0 + tx];
    __syncthreads();
#pragma unroll
    for (int i = ty; i < 32; i += 8)
        out[(size_t)(c0 + i) * R + r0 + tx] = f2bf(tile[tx][i]);
}

extern "C" void kernel_launch(void* const* d_in, const int* in_sizes, int n_in,
                              void* d_out, int out_size, void* d_ws, size_t ws_size,
                              hipStream_t stream) {
    const float* text = (const float*)d_in[0];
    const float* image = (const float*)d_in[1];
    const float* w_text = (const float*)d_in[2];
    const float* b_text = (const float*)d_in[3];
    const float* w_image = (const float*)d_in[4];
    const float* b_image = (const float*)d_in[5];
    const float* scale_TI = (const float*)d_in[6];
    const float* scale_IT = (const float*)d_in[7];
    float* out0 = (float*)d_out;
    float* out1 = out0 + (size_t)N_T * DIM;

    // Workspace layout (needs ~96 MB + 32 KB):
    char* ws = (char*)d_ws;
    unsigned short* t_bf = (unsigned short*)(ws);                       // 8 MB
    unsigned short* i_bf = (unsigned short*)(ws + (8ull << 20));        // 8 MB
    unsigned short* imgT = (unsigned short*)(ws + (16ull << 20));       // 8 MB
    unsigned short* textT = (unsigned short*)(ws + (24ull << 20));      // 8 MB
    float* logits = (float*)(ws + (32ull << 20));                       // 64 MB
    float* lT = (float*)(ws + (96ull << 20));                           // 16 KB
    float* lI = (float*)(ws + (96ull << 20) + 16384);                   // 16 KB

    transpose_cvt<<<dim3(DIM / 32, N_I / 32), 256, 0, stream>>>(image, imgT, N_I, DIM);
    transpose_cvt<<<dim3(DIM / 32, N_T / 32), 256, 0, stream>>>(text, textT, N_T, DIM);

    gemm_proj<<<dim3(N_T / 128, DIM / 128), 256, 0, stream>>>(text, w_text, b_text, t_bf);
    gemm_proj<<<dim3(N_I / 128, DIM / 128), 256, 0, stream>>>(image, w_image, b_image, i_bf);

    gemm_logits<<<dim3(N_T / 128, N_I / 128), 256, 0, stream>>>(t_bf, i_bf, logits);

    row_sums<<<N_T, 256, 0, stream>>>(logits, lT);
    hipMemsetAsync(lI, 0, N_I * sizeof(float), stream);
    col_sums<<<dim3(N_I / 256, N_T / 128), 256, 0, stream>>>(logits, lI);

    attn_TI<<<dim3(N_T / 128, DIM / 128), 256, 0, stream>>>(logits, imgT, lT, scale_TI, out0);
    attn_IT<<<dim3(N_I / 128, DIM / 128), 256, 0, stream>>>(logits, textT, lI, scale_IT, out1);
}

// Round 2
// 459.459 us; speedup vs baseline: 1.3470x; 1.3470x over previous
//
#include <hip/hip_runtime.h>

// ---------------------------------------------------------------------------
// ImageTextModule: dual cross-attention between text and image feature sets.
//   t = text @ w_text^T + b_text ; i = image @ w_image^T + b_image
//   P  = exp((t @ i^T) / 32)  materialized ONCE in bf16, in BOTH layouts
//        (P [Nt x Ni] and PT [Ni x Nt]); row/col sums fused into the same
//        kernel via shuffle-reduce + atomicAdd (|logits| < ~3 -> no max-sub).
//   out0 = (scale_TI / lT) * P  @ image   -> plain bf16 GEMM
//   out1 = (scale_IT / lI) * PT @ text    -> plain bf16 GEMM (no transpose!)
// All GEMMs: bf16 MFMA 16x16x32, fp32 accumulate, 128x128 tile, BK=32.
// Workspace: 96 MB + 32 KB.
// ---------------------------------------------------------------------------

typedef __bf16 bf16x8 __attribute__((ext_vector_type(8)));
typedef float f32x4 __attribute__((ext_vector_type(4)));

#define N_T 4096
#define N_I 4096
#define DIM 1024
#define LDSS 40  // K-loop LDS row stride (bf16): 32 + 8 pad; b128 reads ~2-way free
#define TSS 136  // epilogue tile stride (bf16): 128 + 8; 272 B keeps 16B alignment

__device__ __forceinline__ unsigned short f2bf(float f) {
    unsigned int u = __float_as_uint(f);
    u += 0x7fffu + ((u >> 16) & 1u);  // RNE
    return (unsigned short)(u >> 16);
}

// Stage a 128x32 fp32 tile -> bf16 LDS. 256 thr: row tid>>1, 16-col half tid&1.
__device__ __forceinline__ void stage_f32(const float* __restrict__ src, int ld,
                                          int row0, int k0, unsigned short* dst,
                                          int tid) {
    int r = tid >> 1, c = (tid & 1) << 4;
    const float* p = src + (size_t)(row0 + r) * ld + k0 + c;
    unsigned short* q = dst + r * LDSS + c;
#pragma unroll
    for (int v = 0; v < 4; ++v) {
        float4 f = *(const float4*)(p + v * 4);
        unsigned int p0 = (unsigned int)f2bf(f.x) | ((unsigned int)f2bf(f.y) << 16);
        unsigned int p1 = (unsigned int)f2bf(f.z) | ((unsigned int)f2bf(f.w) << 16);
        *(unsigned int*)(q + v * 4) = p0;
        *(unsigned int*)(q + v * 4 + 2) = p1;
    }
}

// Stage a 128x32 bf16 tile -> LDS (2x uint4 per thread, all b128).
__device__ __forceinline__ void stage_bf16(const unsigned short* __restrict__ src,
                                           int ld, int row0, int k0,
                                           unsigned short* dst, int tid) {
    int r = tid >> 1, c = (tid & 1) << 4;
    const uint4* p = (const uint4*)(src + (size_t)(row0 + r) * ld + k0 + c);
    uint4 x0 = p[0], x1 = p[1];
    *(uint4*)(dst + r * LDSS + c) = x0;
    *(uint4*)(dst + r * LDSS + c + 8) = x1;
}

// One BK=32 MFMA step. Wave w: rows (w>>1)*64, cols (w&1)*64, 4x4 16x16 frags.
__device__ __forceinline__ void mfma_step(const unsigned short* As,
                                          const unsigned short* Bs, f32x4 acc[4][4],
                                          int wrow, int wcol, int lane16, int quad) {
    bf16x8 a[4], b[4];
#pragma unroll
    for (int i = 0; i < 4; ++i) {
        a[i] = *(const bf16x8*)&As[(wrow + i * 16 + lane16) * LDSS + quad * 8];
        b[i] = *(const bf16x8*)&Bs[(wcol + i * 16 + lane16) * LDSS + quad * 8];
    }
#pragma unroll
    for (int i = 0; i < 4; ++i)
#pragma unroll
        for (int j = 0; j < 4; ++j)
            acc[i][j] = __builtin_amdgcn_mfma_f32_16x16x32_bf16(a[i], b[j], acc[i][j], 0, 0, 0);
}

// Coalesced 128x128 bf16 tile store from LDS (stride TSS) to global.
__device__ __forceinline__ void tile_store(const unsigned short* sm,
                                           unsigned short* __restrict__ g, int ld,
                                           int row0, int col0, int tid) {
    int r = tid >> 1, h = (tid & 1) << 6;
    const unsigned short* src = sm + r * TSS + h;
    unsigned short* dst = g + (size_t)(row0 + r) * ld + col0 + h;
#pragma unroll
    for (int v = 0; v < 8; ++v)
        *(uint4*)(dst + v * 8) = *(const uint4*)(src + v * 8);
}

#define GEMM_IDX()                                               \
    int tid = threadIdx.x;                                       \
    int m0 = blockIdx.x * 128, n0 = blockIdx.y * 128;            \
    int lane = tid & 63, wave = tid >> 6;                        \
    int lane16 = lane & 15, quad = lane >> 4;                    \
    int wrow = (wave >> 1) * 64, wcol = (wave & 1) * 64;         \
    f32x4 acc[4][4];                                             \
    {                                                            \
        f32x4 z = {0.f, 0.f, 0.f, 0.f};                          \
        for (int i = 0; i < 4; ++i)                              \
            for (int j = 0; j < 4; ++j) acc[i][j] = z;           \
    }

// ---- projection: C_bf16[4096][1024] = A_f32 @ W_f32^T + bias --------------
__global__ void __launch_bounds__(256, 2)
gemm_proj(const float* __restrict__ A, const float* __restrict__ W,
          const float* __restrict__ bias, unsigned short* __restrict__ C) {
    __shared__ unsigned short As[128 * LDSS];
    __shared__ unsigned short Bs[128 * LDSS];
    GEMM_IDX();
    for (int k0 = 0; k0 < DIM; k0 += 32) {
        stage_f32(A, DIM, m0, k0, As, tid);
        stage_f32(W, DIM, n0, k0, Bs, tid);
        __syncthreads();
        mfma_step(As, Bs, acc, wrow, wcol, lane16, quad);
        __syncthreads();
    }
#pragma unroll
    for (int j = 0; j < 4; ++j) {
        int col = n0 + wcol + j * 16 + lane16;
        float bv = bias[col];
#pragma unroll
        for (int i = 0; i < 4; ++i) {
            int rowb = m0 + wrow + i * 16 + quad * 4;
#pragma unroll
            for (int r = 0; r < 4; ++r)
                C[(size_t)(rowb + r) * DIM + col] = f2bf(acc[i][j][r] + bv);
        }
    }
}

// ---- logits+exp: P/PT bf16 (both layouts) + fused row/col exp-sums --------
__global__ void __launch_bounds__(256, 2)
gemm_logits_exp(const unsigned short* __restrict__ Tb,
                const unsigned short* __restrict__ Ib,
                unsigned short* __restrict__ P, unsigned short* __restrict__ PT,
                float* __restrict__ lT, float* __restrict__ lI) {
    __shared__ unsigned short smem[128 * TSS];  // 34.8 KB, reused by epilogue
    unsigned short* As = smem;
    unsigned short* Bs = smem + 128 * LDSS;
    GEMM_IDX();
    for (int k0 = 0; k0 < DIM; k0 += 32) {
        stage_bf16(Tb, DIM, m0, k0, As, tid);
        stage_bf16(Ib, DIM, n0, k0, Bs, tid);
        __syncthreads();
        mfma_step(As, Bs, acc, wrow, wcol, lane16, quad);
        __syncthreads();
    }
    // p = exp(logit/32) in place (fp32)
#pragma unroll
    for (int i = 0; i < 4; ++i)
#pragma unroll
        for (int j = 0; j < 4; ++j)
#pragma unroll
            for (int r = 0; r < 4; ++r)
                acc[i][j][r] = __expf(acc[i][j][r] * 0.03125f);
    // fused row sums: each wave covers 64 cols for its 64 rows
#pragma unroll
    for (int i = 0; i < 4; ++i)
#pragma unroll
        for (int r = 0; r < 4; ++r) {
            float s = acc[i][0][r] + acc[i][1][r] + acc[i][2][r] + acc[i][3][r];
            s += __shfl_xor(s, 1); s += __shfl_xor(s, 2);
            s += __shfl_xor(s, 4); s += __shfl_xor(s, 8);
            if (lane16 == 0) atomicAdd(&lT[m0 + wrow + i * 16 + quad * 4 + r], s);
        }
    // fused col sums: each wave covers 64 rows for its 64 cols
#pragma unroll
    for (int j = 0; j < 4; ++j) {
        float s = 0.f;
#pragma unroll
        for (int i = 0; i < 4; ++i)
#pragma unroll
            for (int r = 0; r < 4; ++r) s += acc[i][j][r];
        s += __shfl_xor(s, 16); s += __shfl_xor(s, 32);
        if (quad == 0) atomicAdd(&lI[n0 + wcol + j * 16 + lane16], s);
    }
    // pass 1: normal-layout tile -> P (coalesced b128 stores)
    __syncthreads();
#pragma unroll
    for (int i = 0; i < 4; ++i)
#pragma unroll
        for (int j = 0; j < 4; ++j)
#pragma unroll
            for (int r = 0; r < 4; ++r)
                smem[(wrow + i * 16 + quad * 4 + r) * TSS + wcol + j * 16 + lane16] =
                    f2bf(acc[i][j][r]);
    __syncthreads();
    tile_store(smem, P, N_I, m0, n0, tid);
    // pass 2: transposed tile -> PT (b64 LDS writes, coalesced b128 stores)
    __syncthreads();
#pragma unroll
    for (int i = 0; i < 4; ++i)
#pragma unroll
        for (int j = 0; j < 4; ++j) {
            unsigned int lo = (unsigned int)f2bf(acc[i][j][0]) |
                              ((unsigned int)f2bf(acc[i][j][1]) << 16);
            unsigned int hi = (unsigned int)f2bf(acc[i][j][2]) |
                              ((unsigned int)f2bf(acc[i][j][3]) << 16);
            uint2 v; v.x = lo; v.y = hi;
            *(uint2*)&smem[(wcol + j * 16 + lane16) * TSS + wrow + i * 16 + quad * 4] = v;
        }
    __syncthreads();
    tile_store(smem, PT, N_T, n0, m0, tid);
}

// ---- attention: out[m][d] = (scale/l[m]) * sum_k A[m][k] * Bt[d][k] -------
__global__ void __launch_bounds__(256, 2)
gemm_attn(const unsigned short* __restrict__ A, const unsigned short* __restrict__ Bt,
          const float* __restrict__ l, const float* __restrict__ scale,
          float* __restrict__ out) {
    __shared__ unsigned short As[128 * LDSS];
    __shared__ unsigned short Bs[128 * LDSS];
    GEMM_IDX();
    for (int k0 = 0; k0 < 4096; k0 += 32) {
        stage_bf16(A, 4096, m0, k0, As, tid);
        stage_bf16(Bt, 4096, n0, k0, Bs, tid);
        __syncthreads();
        mfma_step(As, Bs, acc, wrow, wcol, lane16, quad);
        __syncthreads();
    }
    float sc = scale[0];
#pragma unroll
    for (int i = 0; i < 4; ++i) {
        int rowb = m0 + wrow + i * 16 + quad * 4;
        float fac[4];
#pragma unroll
        for (int r = 0; r < 4; ++r) fac[r] = sc / l[rowb + r];
#pragma unroll
        for (int j = 0; j < 4; ++j) {
            int col = n0 + wcol + j * 16 + lane16;
#pragma unroll
            for (int r = 0; r < 4; ++r)
                out[(size_t)(rowb + r) * DIM + col] = acc[i][j][r] * fac[r];
        }
    }
}

// ---- transpose + fp32->bf16: in[R][C] -> out[C][R] ------------------------
__global__ void __launch_bounds__(256)
transpose_cvt(const float* __restrict__ in, unsigned short* __restrict__ out,
              int R, int C) {
    __shared__ float tile[32][33];
    int c0 = blockIdx.x * 32, r0 = blockIdx.y * 32;
    int tx = threadIdx.x & 31, ty = threadIdx.x >> 5;  // 32 x 8
#pragma unroll
    for (int i = ty; i < 32; i += 8)
        tile[i][tx] = in[(size_t)(r0 + i) * C + c0 + tx];
    __syncthreads();
#pragma unroll
    for (int i = ty; i < 32; i += 8)
        out[(size_t)(c0 + i) * R + r0 + tx] = f2bf(tile[tx][i]);
}

extern "C" void kernel_launch(void* const* d_in, const int* in_sizes, int n_in,
                              void* d_out, int out_size, void* d_ws, size_t ws_size,
                              hipStream_t stream) {
    const float* text = (const float*)d_in[0];
    const float* image = (const float*)d_in[1];
    const float* w_text = (const float*)d_in[2];
    const float* b_text = (const float*)d_in[3];
    const float* w_image = (const float*)d_in[4];
    const float* b_image = (const float*)d_in[5];
    const float* scale_TI = (const float*)d_in[6];
    const float* scale_IT = (const float*)d_in[7];
    float* out0 = (float*)d_out;
    float* out1 = out0 + (size_t)N_T * DIM;

    // Workspace layout (96 MB + 32 KB):
    char* ws = (char*)d_ws;
    unsigned short* t_bf = (unsigned short*)(ws);                   // 8 MB
    unsigned short* i_bf = (unsigned short*)(ws + (8ull << 20));    // 8 MB
    unsigned short* imgT = (unsigned short*)(ws + (16ull << 20));   // 8 MB
    unsigned short* textT = (unsigned short*)(ws + (24ull << 20));  // 8 MB
    unsigned short* P = (unsigned short*)(ws + (32ull << 20));      // 32 MB
    unsigned short* PT = (unsigned short*)(ws + (64ull << 20));     // 32 MB
    float* lT = (float*)(ws + (96ull << 20));                       // 16 KB
    float* lI = (float*)(ws + (96ull << 20) + 16384);               // 16 KB

    hipMemsetAsync(lT, 0, 32768, stream);  // lT + lI contiguous

    transpose_cvt<<<dim3(DIM / 32, N_I / 32), 256, 0, stream>>>(image, imgT, N_I, DIM);
    transpose_cvt<<<dim3(DIM / 32, N_T / 32), 256, 0, stream>>>(text, textT, N_T, DIM);

    gemm_proj<<<dim3(N_T / 128, DIM / 128), 256, 0, stream>>>(text, w_text, b_text, t_bf);
    gemm_proj<<<dim3(N_I / 128, DIM / 128), 256, 0, stream>>>(image, w_image, b_image, i_bf);

    gemm_logits_exp<<<dim3(N_T / 128, N_I / 128), 256, 0, stream>>>(t_bf, i_bf, P, PT, lT, lI);

    gemm_attn<<<dim3(N_T / 128, DIM / 128), 256, 0, stream>>>(P, imgT, lT, scale_TI, out0);
    gemm_attn<<<dim3(N_I / 128, DIM / 128), 256, 0, stream>>>(PT, textT, lI, scale_IT, out1);
}

// Round 3
// 318.729 us; speedup vs baseline: 1.9418x; 1.4415x over previous
//
#include <hip/hip_runtime.h>

// ---------------------------------------------------------------------------
// ImageTextModule: dual cross-attention between text and image feature sets.
//   t = text @ w_text^T + b_text ; i = image @ w_image^T + b_image  (bf16)
//   P  = exp((t @ i^T) / 32)  materialized ONCE in bf16, BOTH layouts (P, PT);
//        row/col exp-sums fused via shuffle-reduce + atomicAdd (|logit|<~3).
//   out0 = (scale_TI / lT) * P  @ image ; out1 = (scale_IT / lI) * PT @ text
//        -> ONE fused launch, split-K=2 (1024 blocks), atomicAdd epilogue.
// K-loops: m97 structure — 128x128 tile, BK=32, UNPADDED LDS [128][32],
// global_load_lds width-16 async staging, bf16 MFMA 16x16x32, fp32 accum.
// Workspace: 96 MB + 32 KB (cvt buffers overlaid under P; checked disjoint).
// ---------------------------------------------------------------------------

typedef __bf16 bf16x8 __attribute__((ext_vector_type(8)));
typedef float f32x4 __attribute__((ext_vector_type(4)));

#define N_T 4096
#define N_I 4096
#define DIM 1024
#define TSS 136  // epilogue tile stride (bf16): 128 + 8 pad

__device__ __forceinline__ unsigned short f2bf(float f) {
    unsigned int u = __float_as_uint(f);
    u += 0x7fffu + ((u >> 16) & 1u);  // RNE
    return (unsigned short)(u >> 16);
}

// 16-byte async global->LDS DMA (no VGPR round-trip).
__device__ __forceinline__ void async_cp16(const unsigned short* g, unsigned short* l) {
    __builtin_amdgcn_global_load_lds(
        (const __attribute__((address_space(1))) unsigned int*)g,
        (__attribute__((address_space(3))) unsigned int*)l, 16, 0, 0);
}

// Stage 128x32 bf16 tile -> unpadded LDS [128][32]. Thread t: row t>>2,
// 8-elem chunk (t&3)*8; LDS byte dest = 16*t  (wave-uniform base + lane*16 ✓).
__device__ __forceinline__ void stage_async(const unsigned short* __restrict__ src,
                                            int ld, int row0, int k0,
                                            unsigned short* lds, int tid) {
    int r = tid >> 2, c = (tid & 3) << 3;
    const unsigned short* g = src + (size_t)(row0 + r) * ld + k0 + c;
    async_cp16(g, lds + r * 32 + c);
    async_cp16(g + (size_t)64 * ld, lds + (64 + r) * 32 + c);
}

// One BK=32 MFMA step. Wave w: rows (w>>1)*64, cols (w&1)*64, 4x4 16x16 frags.
__device__ __forceinline__ void mfma_step(const unsigned short* As,
                                          const unsigned short* Bs, f32x4 acc[4][4],
                                          int wrow, int wcol, int lane16, int quad) {
    bf16x8 a[4], b[4];
#pragma unroll
    for (int i = 0; i < 4; ++i) {
        a[i] = *(const bf16x8*)&As[(wrow + i * 16 + lane16) * 32 + quad * 8];
        b[i] = *(const bf16x8*)&Bs[(wcol + i * 16 + lane16) * 32 + quad * 8];
    }
#pragma unroll
    for (int i = 0; i < 4; ++i)
#pragma unroll
        for (int j = 0; j < 4; ++j)
            acc[i][j] = __builtin_amdgcn_mfma_f32_16x16x32_bf16(a[i], b[j], acc[i][j], 0, 0, 0);
}

// Coalesced 128x128 bf16 tile store from LDS (stride TSS) to global.
__device__ __forceinline__ void tile_store(const unsigned short* sm,
                                           unsigned short* __restrict__ g, int ld,
                                           int row0, int col0, int tid) {
    int r = tid >> 1, h = (tid & 1) << 6;
    const unsigned short* src = sm + r * TSS + h;
    unsigned short* dst = g + (size_t)(row0 + r) * ld + col0 + h;
#pragma unroll
    for (int v = 0; v < 8; ++v)
        *(uint4*)(dst + v * 8) = *(const uint4*)(src + v * 8);
}

#define GEMM_IDX()                                               \
    int tid = threadIdx.x;                                       \
    int m0 = blockIdx.x * 128, n0 = blockIdx.y * 128;            \
    int lane = tid & 63, wave = tid >> 6;                        \
    int lane16 = lane & 15, quad = lane >> 4;                    \
    int wrow = (wave >> 1) * 64, wcol = (wave & 1) * 64;         \
    f32x4 acc[4][4];                                             \
    {                                                            \
        f32x4 z = {0.f, 0.f, 0.f, 0.f};                          \
        for (int i = 0; i < 4; ++i)                              \
            for (int j = 0; j < 4; ++j) acc[i][j] = z;           \
    }

// ---- bulk fp32 -> bf16 convert of text / image / w_text / w_image ---------
__global__ void __launch_bounds__(256)
cvt_bf16_all(const float* __restrict__ t, const float* __restrict__ im,
             const float* __restrict__ wt, const float* __restrict__ wi,
             unsigned short* __restrict__ tb, unsigned short* __restrict__ imb,
             unsigned short* __restrict__ wtb, unsigned short* __restrict__ wib) {
    size_t i = (size_t)(blockIdx.x * 256 + threadIdx.x) * 8;
    const float* s;
    unsigned short* d;
    size_t off;
    if (i < 4194304)       { s = t;  d = tb;  off = i; }
    else if (i < 8388608)  { s = im; d = imb; off = i - 4194304; }
    else if (i < 9437184)  { s = wt; d = wtb; off = i - 8388608; }
    else                   { s = wi; d = wib; off = i - 9437184; }
    float4 f0 = *(const float4*)(s + off);
    float4 f1 = *(const float4*)(s + off + 4);
    uint4 o;
    o.x = (unsigned int)f2bf(f0.x) | ((unsigned int)f2bf(f0.y) << 16);
    o.y = (unsigned int)f2bf(f0.z) | ((unsigned int)f2bf(f0.w) << 16);
    o.z = (unsigned int)f2bf(f1.x) | ((unsigned int)f2bf(f1.y) << 16);
    o.w = (unsigned int)f2bf(f1.z) | ((unsigned int)f2bf(f1.w) << 16);
    *(uint4*)(d + off) = o;
}

// ---- fused transpose + cvt: {image,text}[4096][1024] -> bf16 [1024][4096] --
__global__ void __launch_bounds__(256)
transpose_cvt2(const float* __restrict__ im, const float* __restrict__ tx,
               unsigned short* __restrict__ imgT, unsigned short* __restrict__ textT) {
    const float* in = blockIdx.z ? tx : im;
    unsigned short* out = blockIdx.z ? textT : imgT;
    __shared__ float tile[32][33];
    int c0 = blockIdx.x * 32, r0 = blockIdx.y * 32;
    int txi = threadIdx.x & 31, tyi = threadIdx.x >> 5;  // 32 x 8
#pragma unroll
    for (int i = tyi; i < 32; i += 8)
        tile[i][txi] = in[(size_t)(r0 + i) * DIM + c0 + txi];
    __syncthreads();
#pragma unroll
    for (int i = tyi; i < 32; i += 8)
        out[(size_t)(c0 + i) * N_T + r0 + txi] = f2bf(tile[txi][i]);
}

// ---- fused projections: C_bf16[4096][1024] = A_bf16 @ W_bf16^T + bias ------
__global__ void __launch_bounds__(256, 2)
gemm_proj2(const unsigned short* __restrict__ Atx, const unsigned short* __restrict__ Wtx,
           const float* __restrict__ btx, unsigned short* __restrict__ Ctx,
           const unsigned short* __restrict__ Aim, const unsigned short* __restrict__ Wim,
           const float* __restrict__ bim, unsigned short* __restrict__ Cim) {
    __shared__ unsigned short As[128 * 32];
    __shared__ unsigned short Bs[128 * 32];
    int z = blockIdx.z;
    const unsigned short* A = z ? Aim : Atx;
    const unsigned short* W = z ? Wim : Wtx;
    const float* bias = z ? bim : btx;
    unsigned short* C = z ? Cim : Ctx;
    GEMM_IDX();
    for (int k0 = 0; k0 < DIM; k0 += 32) {
        stage_async(A, DIM, m0, k0, As, tid);
        stage_async(W, DIM, n0, k0, Bs, tid);
        __syncthreads();
        mfma_step(As, Bs, acc, wrow, wcol, lane16, quad);
        __syncthreads();
    }
#pragma unroll
    for (int j = 0; j < 4; ++j) {
        int col = n0 + wcol + j * 16 + lane16;
        float bv = bias[col];
#pragma unroll
        for (int i = 0; i < 4; ++i) {
            int rowb = m0 + wrow + i * 16 + quad * 4;
#pragma unroll
            for (int r = 0; r < 4; ++r)
                C[(size_t)(rowb + r) * DIM + col] = f2bf(acc[i][j][r] + bv);
        }
    }
}

// ---- logits+exp: P/PT bf16 (both layouts) + fused row/col exp-sums ---------
__global__ void __launch_bounds__(256, 2)
gemm_logits_exp(const unsigned short* __restrict__ Tb,
                const unsigned short* __restrict__ Ib,
                unsigned short* __restrict__ P, unsigned short* __restrict__ PT,
                float* __restrict__ lT, float* __restrict__ lI) {
    __shared__ unsigned short smem[128 * TSS];  // 68 KB, reused by epilogue
    unsigned short* As = smem;
    unsigned short* Bs = smem + 128 * 32;
    GEMM_IDX();
    for (int k0 = 0; k0 < DIM; k0 += 32) {
        stage_async(Tb, DIM, m0, k0, As, tid);
        stage_async(Ib, DIM, n0, k0, Bs, tid);
        __syncthreads();
        mfma_step(As, Bs, acc, wrow, wcol, lane16, quad);
        __syncthreads();
    }
    // p = exp(logit/32) in place (fp32)
#pragma unroll
    for (int i = 0; i < 4; ++i)
#pragma unroll
        for (int j = 0; j < 4; ++j)
#pragma unroll
            for (int r = 0; r < 4; ++r)
                acc[i][j][r] = __expf(acc[i][j][r] * 0.03125f);
    // fused row sums: each wave covers 64 cols for its 64 rows
#pragma unroll
    for (int i = 0; i < 4; ++i)
#pragma unroll
        for (int r = 0; r < 4; ++r) {
            float s = acc[i][0][r] + acc[i][1][r] + acc[i][2][r] + acc[i][3][r];
            s += __shfl_xor(s, 1); s += __shfl_xor(s, 2);
            s += __shfl_xor(s, 4); s += __shfl_xor(s, 8);
            if (lane16 == 0) atomicAdd(&lT[m0 + wrow + i * 16 + quad * 4 + r], s);
        }
    // fused col sums: each wave covers 64 rows for its 64 cols
#pragma unroll
    for (int j = 0; j < 4; ++j) {
        float s = 0.f;
#pragma unroll
        for (int i = 0; i < 4; ++i)
#pragma unroll
            for (int r = 0; r < 4; ++r) s += acc[i][j][r];
        s += __shfl_xor(s, 16); s += __shfl_xor(s, 32);
        if (quad == 0) atomicAdd(&lI[n0 + wcol + j * 16 + lane16], s);
    }
    // pass 1: normal-layout tile -> P (coalesced b128 stores)
    __syncthreads();
#pragma unroll
    for (int i = 0; i < 4; ++i)
#pragma unroll
        for (int j = 0; j < 4; ++j)
#pragma unroll
            for (int r = 0; r < 4; ++r)
                smem[(wrow + i * 16 + quad * 4 + r) * TSS + wcol + j * 16 + lane16] =
                    f2bf(acc[i][j][r]);
    __syncthreads();
    tile_store(smem, P, N_I, m0, n0, tid);
    // pass 2: transposed tile -> PT (b64 LDS writes, coalesced b128 stores)
    __syncthreads();
#pragma unroll
    for (int i = 0; i < 4; ++i)
#pragma unroll
        for (int j = 0; j < 4; ++j) {
            unsigned int lo = (unsigned int)f2bf(acc[i][j][0]) |
                              ((unsigned int)f2bf(acc[i][j][1]) << 16);
            unsigned int hi = (unsigned int)f2bf(acc[i][j][2]) |
                              ((unsigned int)f2bf(acc[i][j][3]) << 16);
            uint2 v; v.x = lo; v.y = hi;
            *(uint2*)&smem[(wcol + j * 16 + lane16) * TSS + wrow + i * 16 + quad * 4] = v;
        }
    __syncthreads();
    tile_store(smem, PT, N_T, n0, m0, tid);
}

// ---- fused attention GEMMs, split-K=2, atomicAdd epilogue ------------------
// z&1: which problem; z>>1: K-slice. out += (scale/l[m]) * A[m][k]*Bt[d][k].
__global__ void __launch_bounds__(256, 2)
gemm_attn2(const unsigned short* __restrict__ P, const unsigned short* __restrict__ imgT,
           const float* __restrict__ lT, const float* __restrict__ sTI,
           float* __restrict__ out0,
           const unsigned short* __restrict__ PT, const unsigned short* __restrict__ textT,
           const float* __restrict__ lI, const float* __restrict__ sIT,
           float* __restrict__ out1) {
    __shared__ unsigned short As[128 * 32];
    __shared__ unsigned short Bs[128 * 32];
    int which = blockIdx.z & 1, ks = blockIdx.z >> 1;
    const unsigned short* A = which ? PT : P;
    const unsigned short* Bt = which ? textT : imgT;
    const float* l = which ? lI : lT;
    const float* sp = which ? sIT : sTI;
    float* out = which ? out1 : out0;
    GEMM_IDX();
    int kbeg = ks * 2048, kend = kbeg + 2048;
    for (int k0 = kbeg; k0 < kend; k0 += 32) {
        stage_async(A, 4096, m0, k0, As, tid);
        stage_async(Bt, 4096, n0, k0, Bs, tid);
        __syncthreads();
        mfma_step(As, Bs, acc, wrow, wcol, lane16, quad);
        __syncthreads();
    }
    float sc = sp[0];
#pragma unroll
    for (int i = 0; i < 4; ++i) {
        int rowb = m0 + wrow + i * 16 + quad * 4;
        float fac[4];
#pragma unroll
        for (int r = 0; r < 4; ++r) fac[r] = sc / l[rowb + r];
#pragma unroll
        for (int j = 0; j < 4; ++j) {
            int col = n0 + wcol + j * 16 + lane16;
#pragma unroll
            for (int r = 0; r < 4; ++r)
                atomicAdd(&out[(size_t)(rowb + r) * DIM + col], acc[i][j][r] * fac[r]);
        }
    }
}

extern "C" void kernel_launch(void* const* d_in, const int* in_sizes, int n_in,
                              void* d_out, int out_size, void* d_ws, size_t ws_size,
                              hipStream_t stream) {
    const float* text = (const float*)d_in[0];
    const float* image = (const float*)d_in[1];
    const float* w_text = (const float*)d_in[2];
    const float* b_text = (const float*)d_in[3];
    const float* w_image = (const float*)d_in[4];
    const float* b_image = (const float*)d_in[5];
    const float* scale_TI = (const float*)d_in[6];
    const float* scale_IT = (const float*)d_in[7];
    float* out0 = (float*)d_out;
    float* out1 = out0 + (size_t)N_T * DIM;

    // Workspace layout (96 MB + 32 KB). cvt buffers [0,20MB) die before
    // gemm_logits_exp writes P over [0,32MB) — lifetimes checked disjoint.
    char* ws = (char*)d_ws;
    unsigned short* text_bf = (unsigned short*)(ws);                 // 8 MB  (dies after proj)
    unsigned short* image_bf = (unsigned short*)(ws + (8ull << 20)); // 8 MB  (dies after proj)
    unsigned short* wt_bf = (unsigned short*)(ws + (16ull << 20));   // 2 MB  (dies after proj)
    unsigned short* wi_bf = (unsigned short*)(ws + (18ull << 20));   // 2 MB  (dies after proj)
    unsigned short* P = (unsigned short*)(ws);                       // 32 MB (logits -> attn)
    unsigned short* imgT = (unsigned short*)(ws + (32ull << 20));    // 8 MB
    unsigned short* textT = (unsigned short*)(ws + (40ull << 20));   // 8 MB
    unsigned short* t_bf = (unsigned short*)(ws + (48ull << 20));    // 8 MB
    unsigned short* i_bf = (unsigned short*)(ws + (56ull << 20));    // 8 MB
    unsigned short* PT = (unsigned short*)(ws + (64ull << 20));      // 32 MB
    float* lT = (float*)(ws + (96ull << 20));                        // 16 KB
    float* lI = (float*)(ws + (96ull << 20) + 16384);                // 16 KB

    hipMemsetAsync(lT, 0, 32768, stream);                       // lT + lI
    hipMemsetAsync(d_out, 0, (size_t)out_size * 4, stream);     // attn atomics

    cvt_bf16_all<<<5120, 256, 0, stream>>>(text, image, w_text, w_image,
                                           text_bf, image_bf, wt_bf, wi_bf);
    transpose_cvt2<<<dim3(DIM / 32, N_T / 32, 2), 256, 0, stream>>>(image, text, imgT, textT);

    gemm_proj2<<<dim3(N_T / 128, DIM / 128, 2), 256, 0, stream>>>(
        text_bf, wt_bf, b_text, t_bf, image_bf, wi_bf, b_image, i_bf);

    gemm_logits_exp<<<dim3(N_T / 128, N_I / 128), 256, 0, stream>>>(t_bf, i_bf, P, PT, lT, lI);

    gemm_attn2<<<dim3(N_T / 128, DIM / 128, 4), 256, 0, stream>>>(
        P, imgT, lT, scale_TI, out0, PT, textT, lI, scale_IT, out1);
}

// Round 4
// 290.619 us; speedup vs baseline: 2.1296x; 1.0967x over previous
//
#include <hip/hip_runtime.h>

// ---------------------------------------------------------------------------
// ImageTextModule: dual cross-attention between text and image feature sets.
//   t = text @ w_text^T + b_text ; i = image @ w_image^T + b_image  (bf16)
//   P  = exp((t @ i^T) / 32)  materialized ONCE in bf16, BOTH layouts (P, PT);
//        row/col exp-sums fused via shuffle-reduce + atomicAdd (|logit|<~3).
//   out0 = (scale_TI / lT) * P  @ image ; out1 = (scale_IT / lI) * PT @ text
//        -> ONE fused launch, grid z=2 (512 blocks = 2/CU), FULL K=4096,
//           plain fp32 stores (split-K atomics removed: 67 MB of atomic RMW
//           was the round-3 bottleneck — MfmaUtil 23% @ 563 TF).
// K-loops: m97 structure — 128x128 tile, BK=32, UNPADDED LDS [128][32],
// global_load_lds width-16 async staging, bf16 MFMA 16x16x32, fp32 accum.
// Workspace: 96 MB + 32 KB (cvt buffers overlaid under P; checked disjoint).
// ---------------------------------------------------------------------------

typedef __bf16 bf16x8 __attribute__((ext_vector_type(8)));
typedef float f32x4 __attribute__((ext_vector_type(4)));

#define N_T 4096
#define N_I 4096
#define DIM 1024
#define TSS 136  // epilogue tile stride (bf16): 128 + 8 pad

__device__ __forceinline__ unsigned short f2bf(float f) {
    unsigned int u = __float_as_uint(f);
    u += 0x7fffu + ((u >> 16) & 1u);  // RNE
    return (unsigned short)(u >> 16);
}

// 16-byte async global->LDS DMA (no VGPR round-trip).
__device__ __forceinline__ void async_cp16(const unsigned short* g, unsigned short* l) {
    __builtin_amdgcn_global_load_lds(
        (const __attribute__((address_space(1))) unsigned int*)g,
        (__attribute__((address_space(3))) unsigned int*)l, 16, 0, 0);
}

// Stage 128x32 bf16 tile -> unpadded LDS [128][32]. Thread t: row t>>2,
// 8-elem chunk (t&3)*8; LDS byte dest = 16*t  (wave-uniform base + lane*16 ✓).
__device__ __forceinline__ void stage_async(const unsigned short* __restrict__ src,
                                            int ld, int row0, int k0,
                                            unsigned short* lds, int tid) {
    int r = tid >> 2, c = (tid & 3) << 3;
    const unsigned short* g = src + (size_t)(row0 + r) * ld + k0 + c;
    async_cp16(g, lds + r * 32 + c);
    async_cp16(g + (size_t)64 * ld, lds + (64 + r) * 32 + c);
}

// One BK=32 MFMA step. Wave w: rows (w>>1)*64, cols (w&1)*64, 4x4 16x16 frags.
__device__ __forceinline__ void mfma_step(const unsigned short* As,
                                          const unsigned short* Bs, f32x4 acc[4][4],
                                          int wrow, int wcol, int lane16, int quad) {
    bf16x8 a[4], b[4];
#pragma unroll
    for (int i = 0; i < 4; ++i) {
        a[i] = *(const bf16x8*)&As[(wrow + i * 16 + lane16) * 32 + quad * 8];
        b[i] = *(const bf16x8*)&Bs[(wcol + i * 16 + lane16) * 32 + quad * 8];
    }
#pragma unroll
    for (int i = 0; i < 4; ++i)
#pragma unroll
        for (int j = 0; j < 4; ++j)
            acc[i][j] = __builtin_amdgcn_mfma_f32_16x16x32_bf16(a[i], b[j], acc[i][j], 0, 0, 0);
}

// Coalesced 128x128 bf16 tile store from LDS (stride TSS) to global.
__device__ __forceinline__ void tile_store(const unsigned short* sm,
                                           unsigned short* __restrict__ g, int ld,
                                           int row0, int col0, int tid) {
    int r = tid >> 1, h = (tid & 1) << 6;
    const unsigned short* src = sm + r * TSS + h;
    unsigned short* dst = g + (size_t)(row0 + r) * ld + col0 + h;
#pragma unroll
    for (int v = 0; v < 8; ++v)
        *(uint4*)(dst + v * 8) = *(const uint4*)(src + v * 8);
}

#define GEMM_IDX()                                               \
    int tid = threadIdx.x;                                       \
    int m0 = blockIdx.x * 128, n0 = blockIdx.y * 128;            \
    int lane = tid & 63, wave = tid >> 6;                        \
    int lane16 = lane & 15, quad = lane >> 4;                    \
    int wrow = (wave >> 1) * 64, wcol = (wave & 1) * 64;         \
    f32x4 acc[4][4];                                             \
    {                                                            \
        f32x4 z = {0.f, 0.f, 0.f, 0.f};                          \
        for (int i = 0; i < 4; ++i)                              \
            for (int j = 0; j < 4; ++j) acc[i][j] = z;           \
    }

// ---- bulk fp32 -> bf16 convert of text / image / w_text / w_image ---------
__global__ void __launch_bounds__(256)
cvt_bf16_all(const float* __restrict__ t, const float* __restrict__ im,
             const float* __restrict__ wt, const float* __restrict__ wi,
             unsigned short* __restrict__ tb, unsigned short* __restrict__ imb,
             unsigned short* __restrict__ wtb, unsigned short* __restrict__ wib) {
    size_t i = (size_t)(blockIdx.x * 256 + threadIdx.x) * 8;
    const float* s;
    unsigned short* d;
    size_t off;
    if (i < 4194304)       { s = t;  d = tb;  off = i; }
    else if (i < 8388608)  { s = im; d = imb; off = i - 4194304; }
    else if (i < 9437184)  { s = wt; d = wtb; off = i - 8388608; }
    else                   { s = wi; d = wib; off = i - 9437184; }
    float4 f0 = *(const float4*)(s + off);
    float4 f1 = *(const float4*)(s + off + 4);
    uint4 o;
    o.x = (unsigned int)f2bf(f0.x) | ((unsigned int)f2bf(f0.y) << 16);
    o.y = (unsigned int)f2bf(f0.z) | ((unsigned int)f2bf(f0.w) << 16);
    o.z = (unsigned int)f2bf(f1.x) | ((unsigned int)f2bf(f1.y) << 16);
    o.w = (unsigned int)f2bf(f1.z) | ((unsigned int)f2bf(f1.w) << 16);
    *(uint4*)(d + off) = o;
}

// ---- fused transpose + cvt: {image,text}[4096][1024] -> bf16 [1024][4096] --
__global__ void __launch_bounds__(256)
transpose_cvt2(const float* __restrict__ im, const float* __restrict__ tx,
               unsigned short* __restrict__ imgT, unsigned short* __restrict__ textT) {
    const float* in = blockIdx.z ? tx : im;
    unsigned short* out = blockIdx.z ? textT : imgT;
    __shared__ float tile[32][33];
    int c0 = blockIdx.x * 32, r0 = blockIdx.y * 32;
    int txi = threadIdx.x & 31, tyi = threadIdx.x >> 5;  // 32 x 8
#pragma unroll
    for (int i = tyi; i < 32; i += 8)
        tile[i][txi] = in[(size_t)(r0 + i) * DIM + c0 + txi];
    __syncthreads();
#pragma unroll
    for (int i = tyi; i < 32; i += 8)
        out[(size_t)(c0 + i) * N_T + r0 + txi] = f2bf(tile[txi][i]);
}

// ---- fused projections: C_bf16[4096][1024] = A_bf16 @ W_bf16^T + bias ------
__global__ void __launch_bounds__(256, 2)
gemm_proj2(const unsigned short* __restrict__ Atx, const unsigned short* __restrict__ Wtx,
           const float* __restrict__ btx, unsigned short* __restrict__ Ctx,
           const unsigned short* __restrict__ Aim, const unsigned short* __restrict__ Wim,
           const float* __restrict__ bim, unsigned short* __restrict__ Cim) {
    __shared__ unsigned short As[128 * 32];
    __shared__ unsigned short Bs[128 * 32];
    int z = blockIdx.z;
    const unsigned short* A = z ? Aim : Atx;
    const unsigned short* W = z ? Wim : Wtx;
    const float* bias = z ? bim : btx;
    unsigned short* C = z ? Cim : Ctx;
    GEMM_IDX();
    for (int k0 = 0; k0 < DIM; k0 += 32) {
        stage_async(A, DIM, m0, k0, As, tid);
        stage_async(W, DIM, n0, k0, Bs, tid);
        __syncthreads();
        mfma_step(As, Bs, acc, wrow, wcol, lane16, quad);
        __syncthreads();
    }
#pragma unroll
    for (int j = 0; j < 4; ++j) {
        int col = n0 + wcol + j * 16 + lane16;
        float bv = bias[col];
#pragma unroll
        for (int i = 0; i < 4; ++i) {
            int rowb = m0 + wrow + i * 16 + quad * 4;
#pragma unroll
            for (int r = 0; r < 4; ++r)
                C[(size_t)(rowb + r) * DIM + col] = f2bf(acc[i][j][r] + bv);
        }
    }
}

// ---- logits+exp: P/PT bf16 (both layouts) + fused row/col exp-sums ---------
__global__ void __launch_bounds__(256, 2)
gemm_logits_exp(const unsigned short* __restrict__ Tb,
                const unsigned short* __restrict__ Ib,
                unsigned short* __restrict__ P, unsigned short* __restrict__ PT,
                float* __restrict__ lT, float* __restrict__ lI) {
    __shared__ unsigned short smem[128 * TSS];  // 34.8 KB, reused by epilogue
    unsigned short* As = smem;
    unsigned short* Bs = smem + 128 * 32;
    GEMM_IDX();
    for (int k0 = 0; k0 < DIM; k0 += 32) {
        stage_async(Tb, DIM, m0, k0, As, tid);
        stage_async(Ib, DIM, n0, k0, Bs, tid);
        __syncthreads();
        mfma_step(As, Bs, acc, wrow, wcol, lane16, quad);
        __syncthreads();
    }
    // p = exp(logit/32) in place (fp32)
#pragma unroll
    for (int i = 0; i < 4; ++i)
#pragma unroll
        for (int j = 0; j < 4; ++j)
#pragma unroll
            for (int r = 0; r < 4; ++r)
                acc[i][j][r] = __expf(acc[i][j][r] * 0.03125f);
    // fused row sums: each wave covers 64 cols for its 64 rows
#pragma unroll
    for (int i = 0; i < 4; ++i)
#pragma unroll
        for (int r = 0; r < 4; ++r) {
            float s = acc[i][0][r] + acc[i][1][r] + acc[i][2][r] + acc[i][3][r];
            s += __shfl_xor(s, 1); s += __shfl_xor(s, 2);
            s += __shfl_xor(s, 4); s += __shfl_xor(s, 8);
            if (lane16 == 0) atomicAdd(&lT[m0 + wrow + i * 16 + quad * 4 + r], s);
        }
    // fused col sums: each wave covers 64 rows for its 64 cols
#pragma unroll
    for (int j = 0; j < 4; ++j) {
        float s = 0.f;
#pragma unroll
        for (int i = 0; i < 4; ++i)
#pragma unroll
            for (int r = 0; r < 4; ++r) s += acc[i][j][r];
        s += __shfl_xor(s, 16); s += __shfl_xor(s, 32);
        if (quad == 0) atomicAdd(&lI[n0 + wcol + j * 16 + lane16], s);
    }
    // pass 1: normal-layout tile -> P (coalesced b128 stores)
    __syncthreads();
#pragma unroll
    for (int i = 0; i < 4; ++i)
#pragma unroll
        for (int j = 0; j < 4; ++j)
#pragma unroll
            for (int r = 0; r < 4; ++r)
                smem[(wrow + i * 16 + quad * 4 + r) * TSS + wcol + j * 16 + lane16] =
                    f2bf(acc[i][j][r]);
    __syncthreads();
    tile_store(smem, P, N_I, m0, n0, tid);
    // pass 2: transposed tile -> PT (b64 LDS writes, coalesced b128 stores)
    __syncthreads();
#pragma unroll
    for (int i = 0; i < 4; ++i)
#pragma unroll
        for (int j = 0; j < 4; ++j) {
            unsigned int lo = (unsigned int)f2bf(acc[i][j][0]) |
                              ((unsigned int)f2bf(acc[i][j][1]) << 16);
            unsigned int hi = (unsigned int)f2bf(acc[i][j][2]) |
                              ((unsigned int)f2bf(acc[i][j][3]) << 16);
            uint2 v; v.x = lo; v.y = hi;
            *(uint2*)&smem[(wcol + j * 16 + lane16) * TSS + wrow + i * 16 + quad * 4] = v;
        }
    __syncthreads();
    tile_store(smem, PT, N_T, n0, m0, tid);
}

// ---- fused attention GEMMs, full K, plain-store epilogue -------------------
// z: which problem. out[m][d] = (scale/l[m]) * sum_k A[m][k] * Bt[d][k].
__global__ void __launch_bounds__(256, 2)
gemm_attn2(const unsigned short* __restrict__ P, const unsigned short* __restrict__ imgT,
           const float* __restrict__ lT, const float* __restrict__ sTI,
           float* __restrict__ out0,
           const unsigned short* __restrict__ PT, const unsigned short* __restrict__ textT,
           const float* __restrict__ lI, const float* __restrict__ sIT,
           float* __restrict__ out1) {
    __shared__ unsigned short As[128 * 32];
    __shared__ unsigned short Bs[128 * 32];
    int which = blockIdx.z;
    const unsigned short* A = which ? PT : P;
    const unsigned short* Bt = which ? textT : imgT;
    const float* l = which ? lI : lT;
    const float* sp = which ? sIT : sTI;
    float* out = which ? out1 : out0;
    GEMM_IDX();
    for (int k0 = 0; k0 < 4096; k0 += 32) {
        stage_async(A, 4096, m0, k0, As, tid);
        stage_async(Bt, 4096, n0, k0, Bs, tid);
        __syncthreads();
        mfma_step(As, Bs, acc, wrow, wcol, lane16, quad);
        __syncthreads();
    }
    float sc = sp[0];
#pragma unroll
    for (int i = 0; i < 4; ++i) {
        int rowb = m0 + wrow + i * 16 + quad * 4;
        float fac[4];
#pragma unroll
        for (int r = 0; r < 4; ++r) fac[r] = sc / l[rowb + r];
#pragma unroll
        for (int j = 0; j < 4; ++j) {
            int col = n0 + wcol + j * 16 + lane16;
#pragma unroll
            for (int r = 0; r < 4; ++r)
                out[(size_t)(rowb + r) * DIM + col] = acc[i][j][r] * fac[r];
        }
    }
}

extern "C" void kernel_launch(void* const* d_in, const int* in_sizes, int n_in,
                              void* d_out, int out_size, void* d_ws, size_t ws_size,
                              hipStream_t stream) {
    const float* text = (const float*)d_in[0];
    const float* image = (const float*)d_in[1];
    const float* w_text = (const float*)d_in[2];
    const float* b_text = (const float*)d_in[3];
    const float* w_image = (const float*)d_in[4];
    const float* b_image = (const float*)d_in[5];
    const float* scale_TI = (const float*)d_in[6];
    const float* scale_IT = (const float*)d_in[7];
    float* out0 = (float*)d_out;
    float* out1 = out0 + (size_t)N_T * DIM;

    // Workspace layout (96 MB + 32 KB). cvt buffers [0,20MB) die before
    // gemm_logits_exp writes P over [0,32MB) — lifetimes checked disjoint.
    char* ws = (char*)d_ws;
    unsigned short* text_bf = (unsigned short*)(ws);                 // 8 MB  (dies after proj)
    unsigned short* image_bf = (unsigned short*)(ws + (8ull << 20)); // 8 MB  (dies after proj)
    unsigned short* wt_bf = (unsigned short*)(ws + (16ull << 20));   // 2 MB  (dies after proj)
    unsigned short* wi_bf = (unsigned short*)(ws + (18ull << 20));   // 2 MB  (dies after proj)
    unsigned short* P = (unsigned short*)(ws);                       // 32 MB (logits -> attn)
    unsigned short* imgT = (unsigned short*)(ws + (32ull << 20));    // 8 MB
    unsigned short* textT = (unsigned short*)(ws + (40ull << 20));   // 8 MB
    unsigned short* t_bf = (unsigned short*)(ws + (48ull << 20));    // 8 MB
    unsigned short* i_bf = (unsigned short*)(ws + (56ull << 20));    // 8 MB
    unsigned short* PT = (unsigned short*)(ws + (64ull << 20));      // 32 MB
    float* lT = (float*)(ws + (96ull << 20));                        // 16 KB
    float* lI = (float*)(ws + (96ull << 20) + 16384);                // 16 KB

    hipMemsetAsync(lT, 0, 32768, stream);  // lT + lI (atomic accumulators)

    cvt_bf16_all<<<5120, 256, 0, stream>>>(text, image, w_text, w_image,
                                           text_bf, image_bf, wt_bf, wi_bf);
    transpose_cvt2<<<dim3(DIM / 32, N_T / 32, 2), 256, 0, stream>>>(image, text, imgT, textT);

    gemm_proj2<<<dim3(N_T / 128, DIM / 128, 2), 256, 0, stream>>>(
        text_bf, wt_bf, b_text, t_bf, image_bf, wi_bf, b_image, i_bf);

    gemm_logits_exp<<<dim3(N_T / 128, N_I / 128), 256, 0, stream>>>(t_bf, i_bf, P, PT, lT, lI);

    gemm_attn2<<<dim3(N_T / 128, DIM / 128, 2), 256, 0, stream>>>(
        P, imgT, lT, scale_TI, out0, PT, textT, lI, scale_IT, out1);
}

// Round 5
// 279.931 us; speedup vs baseline: 2.2109x; 1.0382x over previous
//
#include <hip/hip_runtime.h>

// ---------------------------------------------------------------------------
// ImageTextModule: dual cross-attention between text and image feature sets.
//   t = text @ w_text^T + b_text ; i = image @ w_image^T + b_image  (bf16)
//   P  = exp((t @ i^T) / 32)  materialized ONCE in bf16, BOTH layouts (P, PT);
//        row/col exp-sums fused via shuffle-reduce + atomicAdd (|logit|<~3).
//   out0 = (scale_TI / lT) * P  @ image ; out1 = (scale_IT / lI) * PT @ text
//        -> ONE fused launch, 512-thread blocks with IN-BLOCK split-K=2:
//           waves 0-3 do K[0,2048), waves 4-7 K[2048,4096), merged via a
//           4-chunk LDS reduction, single plain-store epilogue. 16 waves/CU
//           (round-4 counter: Occupancy 20.7% = starved at 8 waves/CU).
// K-loops: m97 structure — 128x128 tile, BK=32, UNPADDED LDS [128][32],
// global_load_lds width-16 async staging, bf16 MFMA 16x16x32, fp32 accum.
// Workspace: 96 MB + 32 KB (cvt buffers overlaid under P; checked disjoint).
// ---------------------------------------------------------------------------

typedef __bf16 bf16x8 __attribute__((ext_vector_type(8)));
typedef float f32x4 __attribute__((ext_vector_type(4)));

#define N_T 4096
#define N_I 4096
#define DIM 1024
#define TSS 136  // epilogue tile stride (bf16): 128 + 8 pad

__device__ __forceinline__ unsigned short f2bf(float f) {
    unsigned int u = __float_as_uint(f);
    u += 0x7fffu + ((u >> 16) & 1u);  // RNE
    return (unsigned short)(u >> 16);
}

// 16-byte async global->LDS DMA (no VGPR round-trip).
__device__ __forceinline__ void async_cp16(const unsigned short* g, unsigned short* l) {
    __builtin_amdgcn_global_load_lds(
        (const __attribute__((address_space(1))) unsigned int*)g,
        (__attribute__((address_space(3))) unsigned int*)l, 16, 0, 0);
}

// Stage 128x32 bf16 tile -> unpadded LDS [128][32] with 256 threads t=0..255:
// row t>>2, 8-elem chunk (t&3)*8; LDS byte dest = 16*t (uniform base+lane*16).
__device__ __forceinline__ void stage_async(const unsigned short* __restrict__ src,
                                            int ld, int row0, int k0,
                                            unsigned short* lds, int t) {
    int r = t >> 2, c = (t & 3) << 3;
    const unsigned short* g = src + (size_t)(row0 + r) * ld + k0 + c;
    async_cp16(g, lds + r * 32 + c);
    async_cp16(g + (size_t)64 * ld, lds + (64 + r) * 32 + c);
}

// One BK=32 MFMA step. Wave w (of 4): rows (w>>1)*64, cols (w&1)*64, 4x4 frags.
__device__ __forceinline__ void mfma_step(const unsigned short* As,
                                          const unsigned short* Bs, f32x4 acc[4][4],
                                          int wrow, int wcol, int lane16, int quad) {
    bf16x8 a[4], b[4];
#pragma unroll
    for (int i = 0; i < 4; ++i) {
        a[i] = *(const bf16x8*)&As[(wrow + i * 16 + lane16) * 32 + quad * 8];
        b[i] = *(const bf16x8*)&Bs[(wcol + i * 16 + lane16) * 32 + quad * 8];
    }
#pragma unroll
    for (int i = 0; i < 4; ++i)
#pragma unroll
        for (int j = 0; j < 4; ++j)
            acc[i][j] = __builtin_amdgcn_mfma_f32_16x16x32_bf16(a[i], b[j], acc[i][j], 0, 0, 0);
}

// Coalesced 128x128 bf16 tile store from LDS (stride TSS) to global.
__device__ __forceinline__ void tile_store(const unsigned short* sm,
                                           unsigned short* __restrict__ g, int ld,
                                           int row0, int col0, int tid) {
    int r = tid >> 1, h = (tid & 1) << 6;
    const unsigned short* src = sm + r * TSS + h;
    unsigned short* dst = g + (size_t)(row0 + r) * ld + col0 + h;
#pragma unroll
    for (int v = 0; v < 8; ++v)
        *(uint4*)(dst + v * 8) = *(const uint4*)(src + v * 8);
}

#define GEMM_IDX()                                               \
    int tid = threadIdx.x;                                       \
    int m0 = blockIdx.x * 128, n0 = blockIdx.y * 128;            \
    int lane = tid & 63, wave = tid >> 6;                        \
    int lane16 = lane & 15, quad = lane >> 4;                    \
    int wrow = (wave >> 1) * 64, wcol = (wave & 1) * 64;         \
    f32x4 acc[4][4];                                             \
    {                                                            \
        f32x4 z = {0.f, 0.f, 0.f, 0.f};                          \
        for (int i = 0; i < 4; ++i)                              \
            for (int j = 0; j < 4; ++j) acc[i][j] = z;           \
    }

// ---- bulk fp32 -> bf16 convert of text / image / w_text / w_image ---------
__global__ void __launch_bounds__(256)
cvt_bf16_all(const float* __restrict__ t, const float* __restrict__ im,
             const float* __restrict__ wt, const float* __restrict__ wi,
             unsigned short* __restrict__ tb, unsigned short* __restrict__ imb,
             unsigned short* __restrict__ wtb, unsigned short* __restrict__ wib) {
    size_t i = (size_t)(blockIdx.x * 256 + threadIdx.x) * 8;
    const float* s;
    unsigned short* d;
    size_t off;
    if (i < 4194304)       { s = t;  d = tb;  off = i; }
    else if (i < 8388608)  { s = im; d = imb; off = i - 4194304; }
    else if (i < 9437184)  { s = wt; d = wtb; off = i - 8388608; }
    else                   { s = wi; d = wib; off = i - 9437184; }
    float4 f0 = *(const float4*)(s + off);
    float4 f1 = *(const float4*)(s + off + 4);
    uint4 o;
    o.x = (unsigned int)f2bf(f0.x) | ((unsigned int)f2bf(f0.y) << 16);
    o.y = (unsigned int)f2bf(f0.z) | ((unsigned int)f2bf(f0.w) << 16);
    o.z = (unsigned int)f2bf(f1.x) | ((unsigned int)f2bf(f1.y) << 16);
    o.w = (unsigned int)f2bf(f1.z) | ((unsigned int)f2bf(f1.w) << 16);
    *(uint4*)(d + off) = o;
}

// ---- fused transpose + cvt: {image,text}[4096][1024] -> bf16 [1024][4096] --
__global__ void __launch_bounds__(256)
transpose_cvt2(const float* __restrict__ im, const float* __restrict__ tx,
               unsigned short* __restrict__ imgT, unsigned short* __restrict__ textT) {
    const float* in = blockIdx.z ? tx : im;
    unsigned short* out = blockIdx.z ? textT : imgT;
    __shared__ float tile[32][33];
    int c0 = blockIdx.x * 32, r0 = blockIdx.y * 32;
    int txi = threadIdx.x & 31, tyi = threadIdx.x >> 5;  // 32 x 8
#pragma unroll
    for (int i = tyi; i < 32; i += 8)
        tile[i][txi] = in[(size_t)(r0 + i) * DIM + c0 + txi];
    __syncthreads();
#pragma unroll
    for (int i = tyi; i < 32; i += 8)
        out[(size_t)(c0 + i) * N_T + r0 + txi] = f2bf(tile[txi][i]);
}

// ---- fused projections: C_bf16[4096][1024] = A_bf16 @ W_bf16^T + bias ------
__global__ void __launch_bounds__(256, 2)
gemm_proj2(const unsigned short* __restrict__ Atx, const unsigned short* __restrict__ Wtx,
           const float* __restrict__ btx, unsigned short* __restrict__ Ctx,
           const unsigned short* __restrict__ Aim, const unsigned short* __restrict__ Wim,
           const float* __restrict__ bim, unsigned short* __restrict__ Cim) {
    __shared__ unsigned short As[128 * 32];
    __shared__ unsigned short Bs[128 * 32];
    int z = blockIdx.z;
    const unsigned short* A = z ? Aim : Atx;
    const unsigned short* W = z ? Wim : Wtx;
    const float* bias = z ? bim : btx;
    unsigned short* C = z ? Cim : Ctx;
    GEMM_IDX();
    for (int k0 = 0; k0 < DIM; k0 += 32) {
        stage_async(A, DIM, m0, k0, As, tid);
        stage_async(W, DIM, n0, k0, Bs, tid);
        __syncthreads();
        mfma_step(As, Bs, acc, wrow, wcol, lane16, quad);
        __syncthreads();
    }
#pragma unroll
    for (int j = 0; j < 4; ++j) {
        int col = n0 + wcol + j * 16 + lane16;
        float bv = bias[col];
#pragma unroll
        for (int i = 0; i < 4; ++i) {
            int rowb = m0 + wrow + i * 16 + quad * 4;
#pragma unroll
            for (int r = 0; r < 4; ++r)
                C[(size_t)(rowb + r) * DIM + col] = f2bf(acc[i][j][r] + bv);
        }
    }
}

// ---- logits+exp: P/PT bf16 (both layouts) + fused row/col exp-sums ---------
__global__ void __launch_bounds__(256, 2)
gemm_logits_exp(const unsigned short* __restrict__ Tb,
                const unsigned short* __restrict__ Ib,
                unsigned short* __restrict__ P, unsigned short* __restrict__ PT,
                float* __restrict__ lT, float* __restrict__ lI) {
    __shared__ unsigned short smem[128 * TSS];  // 34.8 KB, reused by epilogue
    unsigned short* As = smem;
    unsigned short* Bs = smem + 128 * 32;
    GEMM_IDX();
    for (int k0 = 0; k0 < DIM; k0 += 32) {
        stage_async(Tb, DIM, m0, k0, As, tid);
        stage_async(Ib, DIM, n0, k0, Bs, tid);
        __syncthreads();
        mfma_step(As, Bs, acc, wrow, wcol, lane16, quad);
        __syncthreads();
    }
    // p = exp(logit/32) in place (fp32)
#pragma unroll
    for (int i = 0; i < 4; ++i)
#pragma unroll
        for (int j = 0; j < 4; ++j)
#pragma unroll
            for (int r = 0; r < 4; ++r)
                acc[i][j][r] = __expf(acc[i][j][r] * 0.03125f);
    // fused row sums: each wave covers 64 cols for its 64 rows
#pragma unroll
    for (int i = 0; i < 4; ++i)
#pragma unroll
        for (int r = 0; r < 4; ++r) {
            float s = acc[i][0][r] + acc[i][1][r] + acc[i][2][r] + acc[i][3][r];
            s += __shfl_xor(s, 1); s += __shfl_xor(s, 2);
            s += __shfl_xor(s, 4); s += __shfl_xor(s, 8);
            if (lane16 == 0) atomicAdd(&lT[m0 + wrow + i * 16 + quad * 4 + r], s);
        }
    // fused col sums: each wave covers 64 rows for its 64 cols
#pragma unroll
    for (int j = 0; j < 4; ++j) {
        float s = 0.f;
#pragma unroll
        for (int i = 0; i < 4; ++i)
#pragma unroll
            for (int r = 0; r < 4; ++r) s += acc[i][j][r];
        s += __shfl_xor(s, 16); s += __shfl_xor(s, 32);
        if (quad == 0) atomicAdd(&lI[n0 + wcol + j * 16 + lane16], s);
    }
    // pass 1: normal-layout tile -> P (coalesced b128 stores)
    __syncthreads();
#pragma unroll
    for (int i = 0; i < 4; ++i)
#pragma unroll
        for (int j = 0; j < 4; ++j)
#pragma unroll
            for (int r = 0; r < 4; ++r)
                smem[(wrow + i * 16 + quad * 4 + r) * TSS + wcol + j * 16 + lane16] =
                    f2bf(acc[i][j][r]);
    __syncthreads();
    tile_store(smem, P, N_I, m0, n0, tid);
    // pass 2: transposed tile -> PT (b64 LDS writes, coalesced b128 stores)
    __syncthreads();
#pragma unroll
    for (int i = 0; i < 4; ++i)
#pragma unroll
        for (int j = 0; j < 4; ++j) {
            unsigned int lo = (unsigned int)f2bf(acc[i][j][0]) |
                              ((unsigned int)f2bf(acc[i][j][1]) << 16);
            unsigned int hi = (unsigned int)f2bf(acc[i][j][2]) |
                              ((unsigned int)f2bf(acc[i][j][3]) << 16);
            uint2 v; v.x = lo; v.y = hi;
            *(uint2*)&smem[(wcol + j * 16 + lane16) * TSS + wrow + i * 16 + quad * 4] = v;
        }
    __syncthreads();
    tile_store(smem, PT, N_T, n0, m0, tid);
}

// ---- fused attention GEMMs: 512 threads, in-block split-K=2 ---------------
// z: which problem. out[m][d] = (scale/l[m]) * sum_k A[m][k] * Bt[d][k].
// Waves 0-3 accumulate K[0,2048), waves 4-7 K[2048,4096); LDS-merge; store.
__global__ void __launch_bounds__(512, 4)
gemm_attn2(const unsigned short* __restrict__ P, const unsigned short* __restrict__ imgT,
           const float* __restrict__ lT, const float* __restrict__ sTI,
           float* __restrict__ out0,
           const unsigned short* __restrict__ PT, const unsigned short* __restrict__ textT,
           const float* __restrict__ lI, const float* __restrict__ sIT,
           float* __restrict__ out1) {
    __shared__ unsigned short As[2][128 * 32];  // 16 KB (also the merge scratch)
    __shared__ unsigned short Bs[2][128 * 32];  // 16 KB
    int which = blockIdx.z;
    const unsigned short* A = which ? PT : P;
    const unsigned short* Bt = which ? textT : imgT;
    const float* l = which ? lI : lT;
    const float* sp = which ? sIT : sTI;
    float* out = which ? out1 : out0;

    int tid = threadIdx.x;            // 0..511
    int half = tid >> 8;              // K-half (wave-uniform)
    int t = tid & 255;                // index within half-group
    int m0 = blockIdx.x * 128, n0 = blockIdx.y * 128;
    int lane = tid & 63;
    int wv = (tid >> 6) & 3;          // wave within half-group
    int lane16 = lane & 15, quad = lane >> 4;
    int wrow = (wv >> 1) * 64, wcol = (wv & 1) * 64;
    f32x4 acc[4][4];
    {
        f32x4 z = {0.f, 0.f, 0.f, 0.f};
        for (int i = 0; i < 4; ++i)
            for (int j = 0; j < 4; ++j) acc[i][j] = z;
    }

    int kbeg = half * 2048, kend = kbeg + 2048;
    for (int k0 = kbeg; k0 < kend; k0 += 32) {  // 64 lockstep iterations
        stage_async(A, 4096, m0, k0, As[half], t);
        stage_async(Bt, 4096, n0, k0, Bs[half], t);
        __syncthreads();
        mfma_step(As[half], Bs[half], acc, wrow, wcol, lane16, quad);
        __syncthreads();
    }

    // Merge the two K-halves through LDS, 4 chunks of 16 KB (reuse As).
    // Layout stride 16 floats/lane -> 2-way bank aliasing only (free, m136).
    float* red = (float*)As;
#pragma unroll
    for (int i = 0; i < 4; ++i) {
        __syncthreads();
        if (half) {
#pragma unroll
            for (int j = 0; j < 4; ++j)
                *(f32x4*)&red[wv * 1024 + lane * 16 + j * 4] = acc[i][j];
        }
        __syncthreads();
        if (!half) {
#pragma unroll
            for (int j = 0; j < 4; ++j)
                acc[i][j] += *(const f32x4*)&red[wv * 1024 + lane * 16 + j * 4];
        }
    }
    if (half) return;  // no barriers below

    float sc = sp[0];
#pragma unroll
    for (int i = 0; i < 4; ++i) {
        int rowb = m0 + wrow + i * 16 + quad * 4;
        float fac[4];
#pragma unroll
        for (int r = 0; r < 4; ++r) fac[r] = sc / l[rowb + r];
#pragma unroll
        for (int j = 0; j < 4; ++j) {
            int col = n0 + wcol + j * 16 + lane16;
#pragma unroll
            for (int r = 0; r < 4; ++r)
                out[(size_t)(rowb + r) * DIM + col] = acc[i][j][r] * fac[r];
        }
    }
}

extern "C" void kernel_launch(void* const* d_in, const int* in_sizes, int n_in,
                              void* d_out, int out_size, void* d_ws, size_t ws_size,
                              hipStream_t stream) {
    const float* text = (const float*)d_in[0];
    const float* image = (const float*)d_in[1];
    const float* w_text = (const float*)d_in[2];
    const float* b_text = (const float*)d_in[3];
    const float* w_image = (const float*)d_in[4];
    const float* b_image = (const float*)d_in[5];
    const float* scale_TI = (const float*)d_in[6];
    const float* scale_IT = (const float*)d_in[7];
    float* out0 = (float*)d_out;
    float* out1 = out0 + (size_t)N_T * DIM;

    // Workspace layout (96 MB + 32 KB). cvt buffers [0,20MB) die before
    // gemm_logits_exp writes P over [0,32MB) — lifetimes checked disjoint.
    char* ws = (char*)d_ws;
    unsigned short* text_bf = (unsigned short*)(ws);                 // 8 MB  (dies after proj)
    unsigned short* image_bf = (unsigned short*)(ws + (8ull << 20)); // 8 MB  (dies after proj)
    unsigned short* wt_bf = (unsigned short*)(ws + (16ull << 20));   // 2 MB  (dies after proj)
    unsigned short* wi_bf = (unsigned short*)(ws + (18ull << 20));   // 2 MB  (dies after proj)
    unsigned short* P = (unsigned short*)(ws);                       // 32 MB (logits -> attn)
    unsigned short* imgT = (unsigned short*)(ws + (32ull << 20));    // 8 MB
    unsigned short* textT = (unsigned short*)(ws + (40ull << 20));   // 8 MB
    unsigned short* t_bf = (unsigned short*)(ws + (48ull << 20));    // 8 MB
    unsigned short* i_bf = (unsigned short*)(ws + (56ull << 20));    // 8 MB
    unsigned short* PT = (unsigned short*)(ws + (64ull << 20));      // 32 MB
    float* lT = (float*)(ws + (96ull << 20));                        // 16 KB
    float* lI = (float*)(ws + (96ull << 20) + 16384);                // 16 KB

    hipMemsetAsync(lT, 0, 32768, stream);  // lT + lI (atomic accumulators)

    cvt_bf16_all<<<5120, 256, 0, stream>>>(text, image, w_text, w_image,
                                           text_bf, image_bf, wt_bf, wi_bf);
    transpose_cvt2<<<dim3(DIM / 32, N_T / 32, 2), 256, 0, stream>>>(image, text, imgT, textT);

    gemm_proj2<<<dim3(N_T / 128, DIM / 128, 2), 256, 0, stream>>>(
        text_bf, wt_bf, b_text, t_bf, image_bf, wi_bf, b_image, i_bf);

    gemm_logits_exp<<<dim3(N_T / 128, N_I / 128), 256, 0, stream>>>(t_bf, i_bf, P, PT, lT, lI);

    gemm_attn2<<<dim3(N_T / 128, DIM / 128, 2), 512, 0, stream>>>(
        P, imgT, lT, scale_TI, out0, PT, textT, lI, scale_IT, out1);
}

// Round 6
// 270.803 us; speedup vs baseline: 2.2854x; 1.0337x over previous
//
#include <hip/hip_runtime.h>

// ---------------------------------------------------------------------------
// ImageTextModule: dual cross-attention between text and image feature sets.
//   t = text @ w_text^T + b_text ; i = image @ w_image^T + b_image  (bf16)
//   P  = exp((t @ i^T) / 32)  materialized ONCE in bf16, BOTH layouts (P, PT);
//        row/col exp-sums fused via shuffle-reduce + atomicAdd (|logit|<~3).
//   out0 = (scale_TI / lT) * P  @ image ; out1 = (scale_IT / lI) * PT @ text
//        -> ONE fused launch, 512-thr blocks, in-block split-K=2, LDS merge.
// K-loops: m97 structure + 2x k-step unroll over DUAL unpadded [128][32]
// buffer pairs (halves the vmcnt(0)+barrier drains — the residual stall at
// MfmaUtil 30% / Occ 41% in round 5 — while keeping global_load_lds's
// lane-linear dest and the proven LDS bank behavior).
// Pre-pass: text/image fp32 read once (fused cvt+transpose), weights cvt'd
// by a small separate kernel.  Workspace: 96 MB + 32 KB.
// ---------------------------------------------------------------------------

typedef __bf16 bf16x8 __attribute__((ext_vector_type(8)));
typedef float f32x4 __attribute__((ext_vector_type(4)));

#define N_T 4096
#define N_I 4096
#define DIM 1024
#define TSS 136  // epilogue tile stride (bf16): 128 + 8 pad

__device__ __forceinline__ unsigned short f2bf(float f) {
    unsigned int u = __float_as_uint(f);
    u += 0x7fffu + ((u >> 16) & 1u);  // RNE
    return (unsigned short)(u >> 16);
}

// 16-byte async global->LDS DMA (no VGPR round-trip).
__device__ __forceinline__ void async_cp16(const unsigned short* g, unsigned short* l) {
    __builtin_amdgcn_global_load_lds(
        (const __attribute__((address_space(1))) unsigned int*)g,
        (__attribute__((address_space(3))) unsigned int*)l, 16, 0, 0);
}

// Stage 128x32 bf16 tile -> unpadded LDS [128][32] with 256 threads t=0..255:
// row t>>2, 8-elem chunk (t&3)*8; LDS byte dest = 16*t (uniform base+lane*16).
__device__ __forceinline__ void stage_async(const unsigned short* __restrict__ src,
                                            int ld, int row0, int k0,
                                            unsigned short* lds, int t) {
    int r = t >> 2, c = (t & 3) << 3;
    const unsigned short* g = src + (size_t)(row0 + r) * ld + k0 + c;
    async_cp16(g, lds + r * 32 + c);
    async_cp16(g + (size_t)64 * ld, lds + (64 + r) * 32 + c);
}

// One BK=32 MFMA step. Wave w (of 4): rows (w>>1)*64, cols (w&1)*64, 4x4 frags.
__device__ __forceinline__ void mfma_step(const unsigned short* As,
                                          const unsigned short* Bs, f32x4 acc[4][4],
                                          int wrow, int wcol, int lane16, int quad) {
    bf16x8 a[4], b[4];
#pragma unroll
    for (int i = 0; i < 4; ++i) {
        a[i] = *(const bf16x8*)&As[(wrow + i * 16 + lane16) * 32 + quad * 8];
        b[i] = *(const bf16x8*)&Bs[(wcol + i * 16 + lane16) * 32 + quad * 8];
    }
#pragma unroll
    for (int i = 0; i < 4; ++i)
#pragma unroll
        for (int j = 0; j < 4; ++j)
            acc[i][j] = __builtin_amdgcn_mfma_f32_16x16x32_bf16(a[i], b[j], acc[i][j], 0, 0, 0);
}

// Coalesced 128x128 bf16 tile store from LDS (stride TSS) to global.
__device__ __forceinline__ void tile_store(const unsigned short* sm,
                                           unsigned short* __restrict__ g, int ld,
                                           int row0, int col0, int tid) {
    int r = tid >> 1, h = (tid & 1) << 6;
    const unsigned short* src = sm + r * TSS + h;
    unsigned short* dst = g + (size_t)(row0 + r) * ld + col0 + h;
#pragma unroll
    for (int v = 0; v < 8; ++v)
        *(uint4*)(dst + v * 8) = *(const uint4*)(src + v * 8);
}

#define GEMM_IDX()                                               \
    int tid = threadIdx.x;                                       \
    int m0 = blockIdx.x * 128, n0 = blockIdx.y * 128;            \
    int lane = tid & 63, wave = tid >> 6;                        \
    int lane16 = lane & 15, quad = lane >> 4;                    \
    int wrow = (wave >> 1) * 64, wcol = (wave & 1) * 64;         \
    f32x4 acc[4][4];                                             \
    {                                                            \
        f32x4 z = {0.f, 0.f, 0.f, 0.f};                          \
        for (int i = 0; i < 4; ++i)                              \
            for (int j = 0; j < 4; ++j) acc[i][j] = z;           \
    }

// ---- fp32 -> bf16 convert of w_text / w_image (1024x1024 each) ------------
__global__ void __launch_bounds__(256)
cvt_w(const float* __restrict__ wt, const float* __restrict__ wi,
      unsigned short* __restrict__ wtb, unsigned short* __restrict__ wib) {
    size_t i = (size_t)(blockIdx.x * 256 + threadIdx.x) * 8;
    const float* s;
    unsigned short* d;
    size_t off;
    if (i < 1048576) { s = wt; d = wtb; off = i; }
    else             { s = wi; d = wib; off = i - 1048576; }
    float4 f0 = *(const float4*)(s + off);
    float4 f1 = *(const float4*)(s + off + 4);
    uint4 o;
    o.x = (unsigned int)f2bf(f0.x) | ((unsigned int)f2bf(f0.y) << 16);
    o.y = (unsigned int)f2bf(f0.z) | ((unsigned int)f2bf(f0.w) << 16);
    o.z = (unsigned int)f2bf(f1.x) | ((unsigned int)f2bf(f1.y) << 16);
    o.w = (unsigned int)f2bf(f1.z) | ((unsigned int)f2bf(f1.w) << 16);
    *(uint4*)(d + off) = o;
}

// ---- fused cvt + transpose: {image,text} fp32 read ONCE -> bf16 + bf16^T ---
__global__ void __launch_bounds__(256)
cvt_tr_fused(const float* __restrict__ im, const float* __restrict__ tx,
             unsigned short* __restrict__ imb, unsigned short* __restrict__ txb,
             unsigned short* __restrict__ imgT, unsigned short* __restrict__ textT) {
    const float* in = blockIdx.z ? tx : im;
    unsigned short* nb = blockIdx.z ? txb : imb;
    unsigned short* tr = blockIdx.z ? textT : imgT;
    __shared__ float tile[32][33];
    int c0 = blockIdx.x * 32, r0 = blockIdx.y * 32;
    int txi = threadIdx.x & 31, tyi = threadIdx.x >> 5;  // 32 x 8
#pragma unroll
    for (int i = tyi; i < 32; i += 8) {
        float v = in[(size_t)(r0 + i) * DIM + c0 + txi];
        tile[i][txi] = v;
        nb[(size_t)(r0 + i) * DIM + c0 + txi] = f2bf(v);
    }
    __syncthreads();
#pragma unroll
    for (int i = tyi; i < 32; i += 8)
        tr[(size_t)(c0 + i) * N_T + r0 + txi] = f2bf(tile[txi][i]);
}

// ---- fused projections: C_bf16[4096][1024] = A_bf16 @ W_bf16^T + bias ------
__global__ void __launch_bounds__(256, 4)
gemm_proj2(const unsigned short* __restrict__ Atx, const unsigned short* __restrict__ Wtx,
           const float* __restrict__ btx, unsigned short* __restrict__ Ctx,
           const unsigned short* __restrict__ Aim, const unsigned short* __restrict__ Wim,
           const float* __restrict__ bim, unsigned short* __restrict__ Cim) {
    __shared__ unsigned short As[2][128 * 32];
    __shared__ unsigned short Bs[2][128 * 32];
    int z = blockIdx.z;
    const unsigned short* A = z ? Aim : Atx;
    const unsigned short* W = z ? Wim : Wtx;
    const float* bias = z ? bim : btx;
    unsigned short* C = z ? Cim : Ctx;
    GEMM_IDX();
    for (int k0 = 0; k0 < DIM; k0 += 64) {
        stage_async(A, DIM, m0, k0, As[0], tid);
        stage_async(W, DIM, n0, k0, Bs[0], tid);
        stage_async(A, DIM, m0, k0 + 32, As[1], tid);
        stage_async(W, DIM, n0, k0 + 32, Bs[1], tid);
        __syncthreads();
        mfma_step(As[0], Bs[0], acc, wrow, wcol, lane16, quad);
        mfma_step(As[1], Bs[1], acc, wrow, wcol, lane16, quad);
        __syncthreads();
    }
#pragma unroll
    for (int j = 0; j < 4; ++j) {
        int col = n0 + wcol + j * 16 + lane16;
        float bv = bias[col];
#pragma unroll
        for (int i = 0; i < 4; ++i) {
            int rowb = m0 + wrow + i * 16 + quad * 4;
#pragma unroll
            for (int r = 0; r < 4; ++r)
                C[(size_t)(rowb + r) * DIM + col] = f2bf(acc[i][j][r] + bv);
        }
    }
}

// ---- logits+exp: P/PT bf16 (both layouts) + fused row/col exp-sums ---------
__global__ void __launch_bounds__(256, 4)
gemm_logits_exp(const unsigned short* __restrict__ Tb,
                const unsigned short* __restrict__ Ib,
                unsigned short* __restrict__ P, unsigned short* __restrict__ PT,
                float* __restrict__ lT, float* __restrict__ lI) {
    __shared__ unsigned short smem[128 * TSS];  // 34.8 KB: K-loop bufs + epilogue
    unsigned short* As0 = smem;
    unsigned short* Bs0 = smem + 4096;
    unsigned short* As1 = smem + 8192;
    unsigned short* Bs1 = smem + 12288;
    GEMM_IDX();
    for (int k0 = 0; k0 < DIM; k0 += 64) {
        stage_async(Tb, DIM, m0, k0, As0, tid);
        stage_async(Ib, DIM, n0, k0, Bs0, tid);
        stage_async(Tb, DIM, m0, k0 + 32, As1, tid);
        stage_async(Ib, DIM, n0, k0 + 32, Bs1, tid);
        __syncthreads();
        mfma_step(As0, Bs0, acc, wrow, wcol, lane16, quad);
        mfma_step(As1, Bs1, acc, wrow, wcol, lane16, quad);
        __syncthreads();
    }
    // p = exp(logit/32) in place (fp32)
#pragma unroll
    for (int i = 0; i < 4; ++i)
#pragma unroll
        for (int j = 0; j < 4; ++j)
#pragma unroll
            for (int r = 0; r < 4; ++r)
                acc[i][j][r] = __expf(acc[i][j][r] * 0.03125f);
    // fused row sums: each wave covers 64 cols for its 64 rows
#pragma unroll
    for (int i = 0; i < 4; ++i)
#pragma unroll
        for (int r = 0; r < 4; ++r) {
            float s = acc[i][0][r] + acc[i][1][r] + acc[i][2][r] + acc[i][3][r];
            s += __shfl_xor(s, 1); s += __shfl_xor(s, 2);
            s += __shfl_xor(s, 4); s += __shfl_xor(s, 8);
            if (lane16 == 0) atomicAdd(&lT[m0 + wrow + i * 16 + quad * 4 + r], s);
        }
    // fused col sums: each wave covers 64 rows for its 64 cols
#pragma unroll
    for (int j = 0; j < 4; ++j) {
        float s = 0.f;
#pragma unroll
        for (int i = 0; i < 4; ++i)
#pragma unroll
            for (int r = 0; r < 4; ++r) s += acc[i][j][r];
        s += __shfl_xor(s, 16); s += __shfl_xor(s, 32);
        if (quad == 0) atomicAdd(&lI[n0 + wcol + j * 16 + lane16], s);
    }
    // pass 1: normal-layout tile -> P (coalesced b128 stores)
    __syncthreads();
#pragma unroll
    for (int i = 0; i < 4; ++i)
#pragma unroll
        for (int j = 0; j < 4; ++j)
#pragma unroll
            for (int r = 0; r < 4; ++r)
                smem[(wrow + i * 16 + quad * 4 + r) * TSS + wcol + j * 16 + lane16] =
                    f2bf(acc[i][j][r]);
    __syncthreads();
    tile_store(smem, P, N_I, m0, n0, tid);
    // pass 2: transposed tile -> PT (b64 LDS writes, coalesced b128 stores)
    __syncthreads();
#pragma unroll
    for (int i = 0; i < 4; ++i)
#pragma unroll
        for (int j = 0; j < 4; ++j) {
            unsigned int lo = (unsigned int)f2bf(acc[i][j][0]) |
                              ((unsigned int)f2bf(acc[i][j][1]) << 16);
            unsigned int hi = (unsigned int)f2bf(acc[i][j][2]) |
                              ((unsigned int)f2bf(acc[i][j][3]) << 16);
            uint2 v; v.x = lo; v.y = hi;
            *(uint2*)&smem[(wcol + j * 16 + lane16) * TSS + wrow + i * 16 + quad * 4] = v;
        }
    __syncthreads();
    tile_store(smem, PT, N_T, n0, m0, tid);
}

// ---- fused attention GEMMs: 512 threads, in-block split-K=2, 2x unroll ----
// z: which problem. out[m][d] = (scale/l[m]) * sum_k A[m][k] * Bt[d][k].
__global__ void __launch_bounds__(512, 4)
gemm_attn2(const unsigned short* __restrict__ P, const unsigned short* __restrict__ imgT,
           const float* __restrict__ lT, const float* __restrict__ sTI,
           float* __restrict__ out0,
           const unsigned short* __restrict__ PT, const unsigned short* __restrict__ textT,
           const float* __restrict__ lI, const float* __restrict__ sIT,
           float* __restrict__ out1) {
    __shared__ unsigned short As[2][2][128 * 32];  // [half][unroll] 32 KB
    __shared__ unsigned short Bs[2][2][128 * 32];  // 32 KB
    int which = blockIdx.z;
    const unsigned short* A = which ? PT : P;
    const unsigned short* Bt = which ? textT : imgT;
    const float* l = which ? lI : lT;
    const float* sp = which ? sIT : sTI;
    float* out = which ? out1 : out0;

    int tid = threadIdx.x;            // 0..511
    int half = tid >> 8;              // K-half (wave-uniform)
    int t = tid & 255;                // index within half-group
    int m0 = blockIdx.x * 128, n0 = blockIdx.y * 128;
    int lane = tid & 63;
    int wv = (tid >> 6) & 3;          // wave within half-group
    int lane16 = lane & 15, quad = lane >> 4;
    int wrow = (wv >> 1) * 64, wcol = (wv & 1) * 64;
    f32x4 acc[4][4];
    {
        f32x4 z = {0.f, 0.f, 0.f, 0.f};
        for (int i = 0; i < 4; ++i)
            for (int j = 0; j < 4; ++j) acc[i][j] = z;
    }

    int kbeg = half * 2048;
    for (int k0 = kbeg; k0 < kbeg + 2048; k0 += 64) {  // 32 lockstep iterations
        stage_async(A, 4096, m0, k0, As[half][0], t);
        stage_async(Bt, 4096, n0, k0, Bs[half][0], t);
        stage_async(A, 4096, m0, k0 + 32, As[half][1], t);
        stage_async(Bt, 4096, n0, k0 + 32, Bs[half][1], t);
        __syncthreads();
        mfma_step(As[half][0], Bs[half][0], acc, wrow, wcol, lane16, quad);
        mfma_step(As[half][1], Bs[half][1], acc, wrow, wcol, lane16, quad);
        __syncthreads();
    }

    // Merge the two K-halves through LDS, 4 chunks of 16 KB (reuse As).
    // Layout stride 16 floats/lane -> 2-way bank aliasing only (free, m136).
    float* red = (float*)As;
#pragma unroll
    for (int i = 0; i < 4; ++i) {
        __syncthreads();
        if (half) {
#pragma unroll
            for (int j = 0; j < 4; ++j)
                *(f32x4*)&red[wv * 1024 + lane * 16 + j * 4] = acc[i][j];
        }
        __syncthreads();
        if (!half) {
#pragma unroll
            for (int j = 0; j < 4; ++j)
                acc[i][j] += *(const f32x4*)&red[wv * 1024 + lane * 16 + j * 4];
        }
    }
    if (half) return;  // no barriers below

    float sc = sp[0];
#pragma unroll
    for (int i = 0; i < 4; ++i) {
        int rowb = m0 + wrow + i * 16 + quad * 4;
        float fac[4];
#pragma unroll
        for (int r = 0; r < 4; ++r) fac[r] = sc / l[rowb + r];
#pragma unroll
        for (int j = 0; j < 4; ++j) {
            int col = n0 + wcol + j * 16 + lane16;
#pragma unroll
            for (int r = 0; r < 4; ++r)
                out[(size_t)(rowb + r) * DIM + col] = acc[i][j][r] * fac[r];
        }
    }
}

extern "C" void kernel_launch(void* const* d_in, const int* in_sizes, int n_in,
                              void* d_out, int out_size, void* d_ws, size_t ws_size,
                              hipStream_t stream) {
    const float* text = (const float*)d_in[0];
    const float* image = (const float*)d_in[1];
    const float* w_text = (const float*)d_in[2];
    const float* b_text = (const float*)d_in[3];
    const float* w_image = (const float*)d_in[4];
    const float* b_image = (const float*)d_in[5];
    const float* scale_TI = (const float*)d_in[6];
    const float* scale_IT = (const float*)d_in[7];
    float* out0 = (float*)d_out;
    float* out1 = out0 + (size_t)N_T * DIM;

    // Workspace layout (96 MB + 32 KB). cvt buffers [0,20MB) die after proj2;
    // gemm_logits_exp then writes P over [0,32MB) — lifetimes disjoint.
    char* ws = (char*)d_ws;
    unsigned short* text_bf = (unsigned short*)(ws);                 // 8 MB  (dies after proj)
    unsigned short* image_bf = (unsigned short*)(ws + (8ull << 20)); // 8 MB  (dies after proj)
    unsigned short* wt_bf = (unsigned short*)(ws + (16ull << 20));   // 2 MB  (dies after proj)
    unsigned short* wi_bf = (unsigned short*)(ws + (18ull << 20));   // 2 MB  (dies after proj)
    unsigned short* P = (unsigned short*)(ws);                       // 32 MB (logits -> attn)
    unsigned short* imgT = (unsigned short*)(ws + (32ull << 20));    // 8 MB
    unsigned short* textT = (unsigned short*)(ws + (40ull << 20));   // 8 MB
    unsigned short* t_bf = (unsigned short*)(ws + (48ull << 20));    // 8 MB
    unsigned short* i_bf = (unsigned short*)(ws + (56ull << 20));    // 8 MB
    unsigned short* PT = (unsigned short*)(ws + (64ull << 20));      // 32 MB
    float* lT = (float*)(ws + (96ull << 20));                        // 16 KB
    float* lI = (float*)(ws + (96ull << 20) + 16384);                // 16 KB

    hipMemsetAsync(lT, 0, 32768, stream);  // lT + lI (atomic accumulators)

    cvt_w<<<1024, 256, 0, stream>>>(w_text, w_image, wt_bf, wi_bf);
    cvt_tr_fused<<<dim3(DIM / 32, N_T / 32, 2), 256, 0, stream>>>(
        image, text, image_bf, text_bf, imgT, textT);

    gemm_proj2<<<dim3(N_T / 128, DIM / 128, 2), 256, 0, stream>>>(
        text_bf, wt_bf, b_text, t_bf, image_bf, wi_bf, b_image, i_bf);

    gemm_logits_exp<<<dim3(N_T / 128, N_I / 128), 256, 0, stream>>>(t_bf, i_bf, P, PT, lT, lI);

    gemm_attn2<<<dim3(N_T / 128, DIM / 128, 2), 512, 0, stream>>>(
        P, imgT, lT, scale_TI, out0, PT, textT, lI, scale_IT, out1);
}